// Round 7
// baseline (13634.882 us; speedup 1.0000x reference)
//
#include <hip/hip_runtime.h>
#include <hip/hip_bf16.h>

#define Hdim  1024
#define TST   127
#define NPH   508            // 127 steps x 4 levels
#define NWORK 128
#define NGRID 136            // 128 workers + up to 8 fetchers
#define NCLS  50000

typedef __attribute__((ext_vector_type(8))) short    s8v;   // 8 x bf16
typedef __attribute__((ext_vector_type(4))) float    f4v;   // MFMA acc
typedef __attribute__((ext_vector_type(4))) unsigned u4v;
typedef __attribute__((ext_vector_type(2))) unsigned u2v;

// ---- workspace layout (bytes) ----
#define OFF_X0    0ull
#define SZ_X0     ((unsigned long long)TST * 64 * Hdim * 2ull)     // bf16 X0
#define OFF_W0B   (OFF_X0 + SZ_X0)                                  // bf16 W0: 2 MB
#define OFF_GPAY  (OFF_W0B + 2097152ull)                            // 4 slots x 128 KB (L3 payload)
#define OFF_STAGE (OFF_GPAY + 524288ull)                            // 8 xcd x 4 slots x 128 KB (L2 stage)
#define OFF_CTRL  (OFF_STAGE + 4194304ull)                          // memset'd control block
#define CTRL_SZ   4096ull
// CTRL: flags 512*u32 @+0 | ranks 8*u32 @+2048 | wcnt u32 @+2112 | esnap 8*u32 @+2176
#define OFF_EPOCH (OFF_CTRL + CTRL_SZ)                              // 8 x 128B -- NEVER memset (monotone)
#define WS_NEED   (OFF_EPOCH + 1024ull)

__device__ __forceinline__ unsigned short f2b(float f) {
  union { float f; unsigned u; } v; v.f = f;
  return (unsigned short)((v.u + 0x7FFFu + ((v.u >> 16) & 1u)) >> 16);  // RNE
}
__device__ __forceinline__ float b2f(unsigned short u) {
  union { unsigned u; float f; } v; v.u = ((unsigned)u) << 16;
  return v.f;
}
__device__ __forceinline__ float fast_tanh(float x) { return 1.f - 2.f / (__expf(2.f * x) + 1.f); }
__device__ __forceinline__ float fast_sigm(float x) { return 1.f / (1.f + __expf(-x)); }
__device__ __forceinline__ s8v pack8(const float* __restrict__ p) {
  s8v r;
#pragma unroll
  for (int i = 0; i < 8; ++i) r[i] = (short)f2b(p[i]);
  return r;
}

// ---- coherent access helpers ----
__device__ __forceinline__ void st_sc1_u32(unsigned* p, unsigned v) {        // -> L3
  asm volatile("global_store_dword %0, %1, off sc0 sc1" :: "v"(p), "v"(v) : "memory");
}
__device__ __forceinline__ void st_sc1_64(unsigned short* p, u2v v) {        // -> L3
  asm volatile("global_store_dwordx2 %0, %1, off sc0 sc1" :: "v"(p), "v"(v) : "memory");
}
__device__ __forceinline__ void wait_vm0() { asm volatile("s_waitcnt vmcnt(0)" ::: "memory"); }
__device__ __forceinline__ unsigned ld_sc1_u32(const unsigned* p) {          // L3-fresh
  unsigned v;
  asm volatile("global_load_dword %0, %1, off sc0 sc1\n\ts_waitcnt vmcnt(0)" : "=v"(v) : "v"(p) : "memory");
  return v;
}
__device__ __forceinline__ unsigned ld_sc0_u32(const unsigned* p) {          // L2-coherent (own XCD)
  unsigned v;
  asm volatile("global_load_dword %0, %1, off sc0\n\ts_waitcnt vmcnt(0)" : "=v"(v) : "v"(p) : "memory");
  return v;
}
__device__ __forceinline__ void st_bf4(unsigned short* p, float x0, float x1, float x2, float x3) {
  u2v v;
  v[0] = (unsigned)f2b(x0) | ((unsigned)f2b(x1) << 16);
  v[1] = (unsigned)f2b(x2) | ((unsigned)f2b(x3) << 16);
  st_sc1_64(p, v);
}
// poll 8 consecutive u32 flags (per-lane) >= q, loads+drain in ONE asm block
__device__ __forceinline__ int poll8_ge(const unsigned* base, unsigned q) {
  u4v A, B;
  asm volatile("global_load_dwordx4 %0, %2, off sc0 sc1\n\t"
               "global_load_dwordx4 %1, %2, off offset:16 sc0 sc1\n\t"
               "s_waitcnt vmcnt(0)"
               : "=&v"(A), "=&v"(B) : "v"(base) : "memory");
  return (A[0] >= q) & (A[1] >= q) & (A[2] >= q) & (A[3] >= q) &
         (B[0] >= q) & (B[1] >= q) & (B[2] >= q) & (B[3] >= q);
}

// 16 sc1 (L3-direct) loads + drain in ONE asm block (R3 lesson)
#define GL16(B, P) asm volatile(                                        \
  "global_load_dwordx4 %0,  %16, off sc0 sc1\n\t"                       \
  "global_load_dwordx4 %1,  %16, off offset:64 sc0 sc1\n\t"             \
  "global_load_dwordx4 %2,  %16, off offset:128 sc0 sc1\n\t"            \
  "global_load_dwordx4 %3,  %16, off offset:192 sc0 sc1\n\t"            \
  "global_load_dwordx4 %4,  %16, off offset:256 sc0 sc1\n\t"            \
  "global_load_dwordx4 %5,  %16, off offset:320 sc0 sc1\n\t"            \
  "global_load_dwordx4 %6,  %16, off offset:384 sc0 sc1\n\t"            \
  "global_load_dwordx4 %7,  %16, off offset:448 sc0 sc1\n\t"            \
  "global_load_dwordx4 %8,  %16, off offset:512 sc0 sc1\n\t"            \
  "global_load_dwordx4 %9,  %16, off offset:576 sc0 sc1\n\t"            \
  "global_load_dwordx4 %10, %16, off offset:640 sc0 sc1\n\t"            \
  "global_load_dwordx4 %11, %16, off offset:704 sc0 sc1\n\t"            \
  "global_load_dwordx4 %12, %16, off offset:768 sc0 sc1\n\t"            \
  "global_load_dwordx4 %13, %16, off offset:832 sc0 sc1\n\t"            \
  "global_load_dwordx4 %14, %16, off offset:896 sc0 sc1\n\t"            \
  "global_load_dwordx4 %15, %16, off offset:960 sc0 sc1\n\t"            \
  "s_waitcnt vmcnt(0)"                                                  \
  : "=&v"(B[0]), "=&v"(B[1]), "=&v"(B[2]), "=&v"(B[3]),                 \
    "=&v"(B[4]), "=&v"(B[5]), "=&v"(B[6]), "=&v"(B[7]),                 \
    "=&v"(B[8]), "=&v"(B[9]), "=&v"(B[10]), "=&v"(B[11]),               \
    "=&v"(B[12]), "=&v"(B[13]), "=&v"(B[14]), "=&v"(B[15])              \
  : "v"(P) : "memory")

// 16 sc0 (L2-hit) loads + drain in ONE asm block
#define GL16W(B, P) asm volatile(                                       \
  "global_load_dwordx4 %0,  %16, off sc0\n\t"                           \
  "global_load_dwordx4 %1,  %16, off offset:64 sc0\n\t"                 \
  "global_load_dwordx4 %2,  %16, off offset:128 sc0\n\t"                \
  "global_load_dwordx4 %3,  %16, off offset:192 sc0\n\t"                \
  "global_load_dwordx4 %4,  %16, off offset:256 sc0\n\t"                \
  "global_load_dwordx4 %5,  %16, off offset:320 sc0\n\t"                \
  "global_load_dwordx4 %6,  %16, off offset:384 sc0\n\t"                \
  "global_load_dwordx4 %7,  %16, off offset:448 sc0\n\t"                \
  "global_load_dwordx4 %8,  %16, off offset:512 sc0\n\t"                \
  "global_load_dwordx4 %9,  %16, off offset:576 sc0\n\t"                \
  "global_load_dwordx4 %10, %16, off offset:640 sc0\n\t"                \
  "global_load_dwordx4 %11, %16, off offset:704 sc0\n\t"                \
  "global_load_dwordx4 %12, %16, off offset:768 sc0\n\t"                \
  "global_load_dwordx4 %13, %16, off offset:832 sc0\n\t"                \
  "global_load_dwordx4 %14, %16, off offset:896 sc0\n\t"                \
  "global_load_dwordx4 %15, %16, off offset:960 sc0\n\t"                \
  "s_waitcnt vmcnt(0)"                                                  \
  : "=&v"(B[0]), "=&v"(B[1]), "=&v"(B[2]), "=&v"(B[3]),                 \
    "=&v"(B[4]), "=&v"(B[5]), "=&v"(B[6]), "=&v"(B[7]),                 \
    "=&v"(B[8]), "=&v"(B[9]), "=&v"(B[10]), "=&v"(B[11]),               \
    "=&v"(B[12]), "=&v"(B[13]), "=&v"(B[14]), "=&v"(B[15])              \
  : "v"(P) : "memory")

// fetcher: 16 coalesced sc1 loads via 4 base pointers + drain, one block
#define GLF16(B, P0, P1, P2, P3) asm volatile(                          \
  "global_load_dwordx4 %0,  %16, off sc0 sc1\n\t"                       \
  "global_load_dwordx4 %1,  %16, off offset:1024 sc0 sc1\n\t"           \
  "global_load_dwordx4 %2,  %16, off offset:2048 sc0 sc1\n\t"           \
  "global_load_dwordx4 %3,  %16, off offset:3072 sc0 sc1\n\t"           \
  "global_load_dwordx4 %4,  %17, off sc0 sc1\n\t"                       \
  "global_load_dwordx4 %5,  %17, off offset:1024 sc0 sc1\n\t"           \
  "global_load_dwordx4 %6,  %17, off offset:2048 sc0 sc1\n\t"           \
  "global_load_dwordx4 %7,  %17, off offset:3072 sc0 sc1\n\t"           \
  "global_load_dwordx4 %8,  %18, off sc0 sc1\n\t"                       \
  "global_load_dwordx4 %9,  %18, off offset:1024 sc0 sc1\n\t"           \
  "global_load_dwordx4 %10, %18, off offset:2048 sc0 sc1\n\t"           \
  "global_load_dwordx4 %11, %18, off offset:3072 sc0 sc1\n\t"           \
  "global_load_dwordx4 %12, %19, off sc0 sc1\n\t"                       \
  "global_load_dwordx4 %13, %19, off offset:1024 sc0 sc1\n\t"           \
  "global_load_dwordx4 %14, %19, off offset:2048 sc0 sc1\n\t"           \
  "global_load_dwordx4 %15, %19, off offset:3072 sc0 sc1\n\t"           \
  "s_waitcnt vmcnt(0)"                                                  \
  : "=&v"(B[0]), "=&v"(B[1]), "=&v"(B[2]), "=&v"(B[3]),                 \
    "=&v"(B[4]), "=&v"(B[5]), "=&v"(B[6]), "=&v"(B[7]),                 \
    "=&v"(B[8]), "=&v"(B[9]), "=&v"(B[10]), "=&v"(B[11]),               \
    "=&v"(B[12]), "=&v"(B[13]), "=&v"(B[14]), "=&v"(B[15])              \
  : "v"(P0), "v"(P1), "v"(P2), "v"(P3) : "memory")

// ---------------- W0 fp32 -> bf16 ----------------
__global__ __launch_bounds__(256) void k_cvt(const float* __restrict__ src,
                                             unsigned short* __restrict__ dst) {
  const int i = (blockIdx.x * 256 + threadIdx.x) * 4;
  float4 v = *(const float4*)(src + i);
  ushort4 o; o.x = f2b(v.x); o.y = f2b(v.y); o.z = f2b(v.z); o.w = f2b(v.w);
  *(ushort4*)(dst + i) = o;
}

// ---------------- X0[t] = emb[idx[:,t+1]] @ W0^T + b0 + bs0, bf16 out ----------------
__global__ __launch_bounds__(256) void k_x0(const float* __restrict__ emb,
                                            const int* __restrict__ ids,
                                            const unsigned short* __restrict__ w0b,
                                            const float* __restrict__ b0,
                                            const float* __restrict__ bs,
                                            unsigned short* __restrict__ x0b) {
  const int t  = blockIdx.x;            // 0..126
  const int cb = blockIdx.y * 256;
  const int lane = threadIdx.x & 63, wvv = threadIdx.x >> 6;
  const int lc = lane & 15, lg = lane >> 4;
  const int cw = cb + wvv * 64;
  const float* erow[4];
#pragma unroll
  for (int rt = 0; rt < 4; ++rt)
    erow[rt] = emb + (size_t)ids[(rt * 16 + lc) * 128 + t + 1] * Hdim + lg * 8;
  f4v acc[4][4];   // [ct][rt]
#pragma unroll
  for (int ct = 0; ct < 4; ++ct)
#pragma unroll
    for (int rt = 0; rt < 4; ++rt) acc[ct][rt] = (f4v){0.f, 0.f, 0.f, 0.f};

  for (int ks = 0; ks < 32; ++ks) {
    s8v bf[4];
#pragma unroll
    for (int rt = 0; rt < 4; ++rt) bf[rt] = pack8(erow[rt] + ks * 32);
#pragma unroll
    for (int ct = 0; ct < 4; ++ct) {
      s8v a = *(const s8v*)(w0b + (size_t)(cw + ct * 16 + lc) * Hdim + ks * 32 + lg * 8);
#pragma unroll
      for (int rt = 0; rt < 4; ++rt)
        acc[ct][rt] = __builtin_amdgcn_mfma_f32_16x16x32_bf16(a, bf[rt], acc[ct][rt], 0, 0, 0);
    }
  }
  unsigned short* xt = x0b + (size_t)t * (64 * Hdim);
#pragma unroll
  for (int ct = 0; ct < 4; ++ct) {
    const int colq = cw + ct * 16 + lg * 4;
    float4 bias = *(const float4*)(b0 + colq);
    float4 bsv  = *(const float4*)(bs + colq);     // bs row 0
#pragma unroll
    for (int rt = 0; rt < 4; ++rt) {
      const int row = rt * 16 + lc;
      ushort4 o;
      o.x = f2b(acc[ct][rt][0] + bias.x + bsv.x);
      o.y = f2b(acc[ct][rt][1] + bias.y + bsv.y);
      o.z = f2b(acc[ct][rt][2] + bias.z + bsv.z);
      o.w = f2b(acc[ct][rt][3] + bias.w + bsv.w);
      *(ushort4*)(xt + (size_t)row * Hdim + colq) = o;
    }
  }
}

// worker GEMM slice: 32 k-chunks; A-frag row = lc&7 (8 real cols, rows 8..15 dup
// and discarded by the lg<2 store guard). SC1 selects payload path (fallback vs L2).
template<int MP, int MS, bool SC1>
__device__ __forceinline__ void level_mm(const unsigned short* stq,
                                         const unsigned short* ldsW,
                                         int lc, int lg, f4v& a1, f4v& a2) {
  s8v bb[16];
  if constexpr (SC1) { GL16(bb, stq); } else { GL16W(bb, stq); }
  __builtin_amdgcn_sched_barrier(0);
#pragma unroll
  for (int k = 0; k < 16; ++k) {
    s8v wA = *(const s8v*)(ldsW + (((MP * 128) + k * 4 + lg) * 8 + (lc & 7)) * 8);
    a1 = __builtin_amdgcn_mfma_f32_16x16x32_bf16(wA, bb[k], a1, 0, 0, 0);
    if constexpr (MS >= 0) {
      s8v wB = *(const s8v*)(ldsW + (((MS * 128) + k * 4 + lg) * 8 + (lc & 7)) * 8);
      a2 = __builtin_amdgcn_mfma_f32_16x16x32_bf16(wB, bb[k], a2, 0, 0, 0);
    }
  }
  if constexpr (SC1) { GL16(bb, stq + 512); } else { GL16W(bb, stq + 512); }
  __builtin_amdgcn_sched_barrier(0);
#pragma unroll
  for (int k = 0; k < 16; ++k) {
    s8v wA = *(const s8v*)(ldsW + (((MP * 128) + (16 + k) * 4 + lg) * 8 + (lc & 7)) * 8);
    a1 = __builtin_amdgcn_mfma_f32_16x16x32_bf16(wA, bb[k], a1, 0, 0, 0);
    if constexpr (MS >= 0) {
      s8v wB = *(const s8v*)(ldsW + (((MS * 128) + (16 + k) * 4 + lg) * 8 + (lc & 7)) * 8);
      a2 = __builtin_amdgcn_mfma_f32_16x16x32_bf16(wB, bb[k], a2, 0, 0, 0);
    }
  }
}

template<bool SC1>
__device__ __forceinline__ void do_phase(unsigned q, const unsigned short* stq,
                                         unsigned short* gp,
                                         const unsigned short* x0b,
                                         const unsigned short* ldsW,
                                         int lc, int lg, int row, int colb,
                                         const float4& b_n2, const float4& b_n3,
                                         const float4& b_n4, const float4& b_n5,
                                         const float4& b_n6, const float* cw,
                                         f4v& r2, f4v& r4) {
  const int lvl = (int)((q - 1u) & 3u);
  f4v acc = (f4v){0.f, 0.f, 0.f, 0.f}, acc2 = acc;
  if (lvl == 0) {                                 // n1 = tanh(M0 h + X0[t])
    level_mm<0, -1, SC1>(stq, ldsW, lc, lg, acc, acc2);
    if (lg < 2) {
      const int t = (int)((q - 1u) >> 2);
      ushort4 xu = *(const ushort4*)(x0b + (size_t)t * 65536 + (size_t)row * Hdim + colb);
      st_bf4(gp + colb,
             fast_tanh(acc[0] + b2f(xu.x)), fast_tanh(acc[1] + b2f(xu.y)),
             fast_tanh(acc[2] + b2f(xu.z)), fast_tanh(acc[3] + b2f(xu.w)));
    }
  } else if (lvl == 1) {                          // n3 = sigm(M2 n1 + b2); n2 regs
    level_mm<2, 1, SC1>(stq, ldsW, lc, lg, acc, acc2);
    if (lg < 2) {
      st_bf4(gp + colb,
             fast_sigm(acc[0] + b_n3.x), fast_sigm(acc[1] + b_n3.y),
             fast_sigm(acc[2] + b_n3.z), fast_sigm(acc[3] + b_n3.w));
      r2[0] = fmaxf(acc2[0] + b_n2.x, 0.f); r2[1] = fmaxf(acc2[1] + b_n2.y, 0.f);
      r2[2] = fmaxf(acc2[2] + b_n2.z, 0.f); r2[3] = fmaxf(acc2[3] + b_n2.w, 0.f);
    }
  } else if (lvl == 2) {                          // n5 = relu(M4 n3 + b4); n4 regs
    level_mm<4, 3, SC1>(stq, ldsW, lc, lg, acc, acc2);
    if (lg < 2) {
      st_bf4(gp + colb,
             fmaxf(acc[0] + b_n5.x, 0.f), fmaxf(acc[1] + b_n5.y, 0.f),
             fmaxf(acc[2] + b_n5.z, 0.f), fmaxf(acc[3] + b_n5.w, 0.f));
      r4[0] = fast_tanh(acc2[0] + b_n4.x); r4[1] = fast_tanh(acc2[1] + b_n4.y);
      r4[2] = fast_tanh(acc2[2] + b_n4.z); r4[3] = fast_tanh(acc2[3] + b_n4.w);
    }
  } else {                                        // n6 = tanh(M5 n5 + b5); h' = combine
    level_mm<5, -1, SC1>(stq, ldsW, lc, lg, acc, acc2);
    if (lg < 2) {
      float h0v = cw[0] * r2[0] + cw[1] * r4[0] + cw[2] * fast_tanh(acc[0] + b_n6.x);
      float h1v = cw[0] * r2[1] + cw[1] * r4[1] + cw[2] * fast_tanh(acc[1] + b_n6.y);
      float h2v = cw[0] * r2[2] + cw[1] * r4[2] + cw[2] * fast_tanh(acc[2] + b_n6.z);
      float h3v = cw[0] * r2[3] + cw[1] * r4[3] + cw[2] * fast_tanh(acc[3] + b_n6.w);
      st_bf4(gp + colb, h0v, h1v, h2v, h3v);
    }
  }
}

// ---------------- persistent scan: workers + per-XCD fetchers ----------------
__global__ __launch_bounds__(256, 1) void k_scan(const float* __restrict__ Ws,
                                                 const float* __restrict__ bs,
                                                 const float* __restrict__ h_in,
                                                 const float* __restrict__ Wsum,
                                                 const float* __restrict__ bsum,
                                                 const float* __restrict__ act,
                                                 char* __restrict__ ws) {
  __shared__ unsigned short ldsW[6 * 128 * 64];   // 96 KiB: 6 mats x 8 cols x 1024 k
  __shared__ int s_info[4];
  const int tid = threadIdx.x;
  const int lane = tid & 63, wvv = tid >> 6;
  const int lc = lane & 15, lg = lane >> 4;

  unsigned* flags = (unsigned*)(ws + OFF_CTRL);
  unsigned* ranks = (unsigned*)(ws + OFF_CTRL + 2048);
  unsigned* wcnt  = (unsigned*)(ws + OFF_CTRL + 2112);
  unsigned* esnap = (unsigned*)(ws + OFF_CTRL + 2176);
  unsigned short* gpay = (unsigned short*)(ws + OFF_GPAY);
  unsigned short* stg0 = (unsigned short*)(ws + OFF_STAGE);
  const unsigned short* x0b = (const unsigned short*)(ws + OFF_X0);

  // ---- role election: physical XCD (s_getreg XCC_ID); first WG per XCD = fetcher ----
  if (tid == 0) {
    unsigned x;
    asm volatile("s_getreg_b32 %0, hwreg(HW_REG_XCC_ID)" : "=s"(x));
    x &= 7u;
    unsigned r = __hip_atomic_fetch_add(&ranks[x], 1u, __ATOMIC_RELAXED, __HIP_MEMORY_SCOPE_AGENT);
    int wi = -1;
    if (r != 0)
      wi = (int)__hip_atomic_fetch_add(wcnt, 1u, __ATOMIC_RELAXED, __HIP_MEMORY_SCOPE_AGENT);
    s_info[0] = (int)x; s_info[1] = (int)r; s_info[2] = wi;
  }
  __syncthreads();
  const int xcd = s_info[0];
  unsigned* epoch_p = (unsigned*)(ws + OFF_EPOCH + (size_t)xcd * 128);
  const unsigned* fp = flags + (size_t)lane * 8;   // this lane's 8 flags to poll

  if (s_info[1] == 0) {
    // ================= FETCHER: L3 payload -> own-L2 stage, monotone epoch =================
    if (tid == 0) {
      // FIX vs R5: read epoch base with sc0 -- the dirty line from the previous
      // replay lives in THIS XCD's L2; sc1 would read a stale L3 copy.
      unsigned eb = ld_sc0_u32(epoch_p);
      st_sc1_u32(esnap + xcd, eb + 1u);            // handshake (memset'd slot, sc1-fresh)
      s_info[3] = (int)eb;
    }
    __syncthreads();
    const unsigned eb = (unsigned)s_info[3];
    for (unsigned q = 1; q <= NPH; ++q) {
      if (wvv == 0) {                              // wave0 polls all 512 flags
        int g = 0;
        while (!__all(poll8_ge(fp, q))) { if (++g >= (1 << 20)) break; }
      }
      __syncthreads();                             // payload q confirmed complete
      char* src = (char*)gpay + (size_t)(q & 3) * 131072 + wvv * 32768 + lane * 16;
      char* dst = (char*)stg0 + ((size_t)xcd * 4 + (q & 3)) * 131072 + wvv * 32768 + lane * 16;
      u4v bb[16];
      GLF16(bb, src, src + 4096, src + 8192, src + 12288);
#pragma unroll
      for (int i = 0; i < 16; ++i)
        *(u4v*)(dst + (i >> 2) * 4096 + (i & 3) * 1024) = bb[i];   // plain -> dirty in OWN L2
      GLF16(bb, src + 16384, src + 20480, src + 24576, src + 28672);
#pragma unroll
      for (int i = 0; i < 16; ++i)
        *(u4v*)(dst + 16384 + (i >> 2) * 4096 + (i & 3) * 1024) = bb[i];
      wait_vm0();                                  // restage resident in L2
      __syncthreads();
      if (tid == 0) *(volatile unsigned*)epoch_p = eb + q;   // plain store: L2-visible, monotone
    }
    return;
  }
  const int widx = s_info[2];
  if (widx >= NWORK) return;                       // spare WG

  // ================= WORKER =================
  const int c0w = widx * 8;
  const int row = wvv * 16 + lc;
  const int colb = c0w + lg * 4;                   // valid for lg<2 only
  unsigned* flg = flags + (size_t)widx * 4 + wvv;

  // LDS: 6 matrices x 8 cols, tiled [mat][kb=k/8][col8][k%8]
  for (int idx = tid; idx < 12288; idx += 256) {
    const int mat = idx / 2048, rem = idx % 2048, c = rem / 256, k4 = rem % 256;
    float4 v = *(const float4*)(Ws + (size_t)mat * (Hdim * Hdim) + (size_t)(c0w + c) * Hdim + k4 * 4);
    ushort4 o; o.x = f2b(v.x); o.y = f2b(v.y); o.z = f2b(v.z); o.w = f2b(v.w);
    *(ushort4*)(ldsW + (((size_t)mat * 128 + (k4 >> 1)) * 8 + c) * 8 + (k4 & 1) * 4) = o;
  }
  float4 bz = (float4){0.f, 0.f, 0.f, 0.f};
  float4 b_n2 = bz, b_n3 = bz, b_n4 = bz, b_n5 = bz, b_n6 = bz;
  if (lg < 2) {
    b_n2 = *(const float4*)(bs + 1 * Hdim + colb);
    b_n3 = *(const float4*)(bs + 2 * Hdim + colb);
    b_n4 = *(const float4*)(bs + 3 * Hdim + colb);
    b_n5 = *(const float4*)(bs + 4 * Hdim + colb);
    b_n6 = *(const float4*)(bs + 5 * Hdim + colb);
  }
  float cw[3];
#pragma unroll
  for (int j = 0; j < 3; ++j) {
    const int i = 2 * j + 1;
    float s = bsum[i];
    for (int a2 = 0; a2 < 12; ++a2) s += Wsum[i * 12 + a2] * act[a2];
    cw[j] = s;
  }
  {
    float m = fmaxf(cw[0], fmaxf(cw[1], cw[2]));
    float e0 = __expf(cw[0] - m), e1 = __expf(cw[1] - m), e2 = __expf(cw[2] - m);
    float inv = 1.f / (e0 + e1 + e2);
    cw[0] = e0 * inv; cw[1] = e1 * inv; cw[2] = e2 * inv;
  }
  __syncthreads();                                 // LDS ready

  // publish h0 slice as payload for phase 1 (slot 1), flag = 1 per wave
  if (lg < 2) {
    float4 hv = *(const float4*)(h_in + (size_t)row * Hdim + colb);
    st_bf4(gpay + 1 * 65536 + (size_t)row * Hdim + colb, hv.x, hv.y, hv.z, hv.w);
  }
  wait_vm0();
  if (lane == 0) st_sc1_u32(flg, 1u);

  // epoch-base handshake; timeout -> permanent sc1 fallback (correct, slower)
  bool l2mode = true; unsigned ebase = 0;
  {
    int g = 0; unsigned s;
    for (;;) {
      s = ld_sc1_u32(esnap + xcd);
      if (s != 0u) { ebase = s - 1u; break; }
      if (++g >= (1 << 16)) { l2mode = false; break; }
    }
  }
  const unsigned short* stg = stg0 + (size_t)xcd * 4 * 65536;
  f4v r2 = (f4v){0.f, 0.f, 0.f, 0.f}, r4 = r2;

  for (unsigned q = 1; q <= NPH; ++q) {
    if (l2mode) {                                  // cheap own-L2 poll
      int g = 0;
      for (;;) {
        unsigned e = ld_sc0_u32(epoch_p);
        if ((unsigned)(e - ebase) >= q) break;
        if (++g >= 16384) { l2mode = false; break; }
      }
    }
    if (!l2mode) {                                 // fallback: global flag poll
      int g = 0;
      while (!__all(poll8_ge(fp, q))) { if (++g >= (1 << 20)) break; }
    }
    unsigned short* gp = gpay + (size_t)((q + 1) & 3) * 65536 + (size_t)row * Hdim;
    if (l2mode) {
      const unsigned short* stq = stg + (size_t)(q & 3) * 65536 + (size_t)row * Hdim + lg * 8;
      do_phase<false>(q, stq, gp, x0b, ldsW, lc, lg, row, colb,
                      b_n2, b_n3, b_n4, b_n5, b_n6, cw, r2, r4);
    } else {
      const unsigned short* stq = gpay + (size_t)(q & 3) * 65536 + (size_t)row * Hdim + lg * 8;
      do_phase<true>(q, stq, gp, x0b, ldsW, lc, lg, row, colb,
                     b_n2, b_n3, b_n4, b_n5, b_n6, cw, r2, r4);
    }
    wait_vm0();                                    // slab visible at L3
    if (lane == 0) st_sc1_u32(flg, q + 1u);
  }
}

// ---------------- epilogue: out = h @ W_out^T + b_out ----------------
__global__ __launch_bounds__(256) void k_out(const unsigned short* __restrict__ hb,
                                             const float* __restrict__ wout,
                                             const float* __restrict__ bout,
                                             float* __restrict__ out) {
  const int cb = blockIdx.x * 128;
  const int lane = threadIdx.x & 63, wvv = threadIdx.x >> 6;
  const int lc = lane & 15, lg = lane >> 4;
  const int cw = cb + wvv * 32;
  f4v acc[4][2];
#pragma unroll
  for (int rt = 0; rt < 4; ++rt)
#pragma unroll
    for (int ct = 0; ct < 2; ++ct) acc[rt][ct] = (f4v){0.f, 0.f, 0.f, 0.f};

  for (int ks = 0; ks < 32; ++ks) {
    s8v a[4];
#pragma unroll
    for (int rt = 0; rt < 4; ++rt)
      a[rt] = *(const s8v*)(hb + (rt * 16 + lc) * Hdim + ks * 32 + lg * 8);
#pragma unroll
    for (int ct = 0; ct < 2; ++ct) {
      const int col = cw + ct * 16 + lc;
      const int cs = col < NCLS ? col : NCLS - 1;
      s8v b = pack8(wout + (size_t)cs * Hdim + ks * 32 + lg * 8);
#pragma unroll
      for (int rt = 0; rt < 4; ++rt)
        acc[rt][ct] = __builtin_amdgcn_mfma_f32_16x16x32_bf16(a[rt], b, acc[rt][ct], 0, 0, 0);
    }
  }
#pragma unroll
  for (int ct = 0; ct < 2; ++ct) {
    const int col = cw + ct * 16 + lc;
    if (col < NCLS) {
      const float bias = bout[col];
#pragma unroll
      for (int rt = 0; rt < 4; ++rt)
#pragma unroll
        for (int j = 0; j < 4; ++j)
          out[(size_t)(rt * 16 + lg * 4 + j) * NCLS + col] = acc[rt][ct][j] + bias;
    }
  }
}

extern "C" void kernel_launch(void* const* d_in, const int* in_sizes, int n_in,
                              void* d_out, int out_size, void* d_ws, size_t ws_size,
                              hipStream_t stream) {
  (void)in_sizes; (void)n_in; (void)out_size;
  if (ws_size < WS_NEED) return;

  const float* emb  = (const float*)d_in[0];
  const float* h0   = (const float*)d_in[1];
  const int*   ids  = (const int*)d_in[2];
  const float* W0   = (const float*)d_in[3];
  const float* b0   = (const float*)d_in[4];
  const float* Ws   = (const float*)d_in[5];
  const float* bsp  = (const float*)d_in[6];
  const float* Wout = (const float*)d_in[7];
  const float* bout = (const float*)d_in[8];
  const float* Wsum = (const float*)d_in[9];
  const float* bsum = (const float*)d_in[10];
  const float* actv = (const float*)d_in[11];
  char* ws  = (char*)d_ws;
  float* out = (float*)d_out;

  // reset flags/ranks/wcnt/esnap. Epoch region deliberately NOT reset (monotone).
  hipMemsetAsync(ws + OFF_CTRL, 0, CTRL_SZ, stream);
  k_cvt<<<1024, 256, 0, stream>>>(W0, (unsigned short*)(ws + OFF_W0B));
  k_x0<<<dim3(TST, 4), 256, 0, stream>>>(emb, ids, (const unsigned short*)(ws + OFF_W0B),
                                         b0, bsp, (unsigned short*)(ws + OFF_X0));

  void* args[] = { (void*)&Ws, (void*)&bsp, (void*)&h0, (void*)&Wsum,
                   (void*)&bsum, (void*)&actv, (void*)&ws };
  hipLaunchCooperativeKernel((void*)k_scan, dim3(NGRID), dim3(256), args, 0, stream);

  // final h = payload of phase 509 -> slot (509 & 3) = 1
  k_out<<<391, 256, 0, stream>>>((const unsigned short*)(ws + OFF_GPAY) + 65536,
                                 Wout, bout, out);
}

// Round 10
// 5018.813 us; speedup vs baseline: 2.7168x; 2.7168x over previous
//
#include <hip/hip_runtime.h>
#include <hip/hip_bf16.h>

#define Hdim 1024
#define TST  127
#define NWG  96
#define NCLS 50000
#define POLL_GUARD (1 << 17)

typedef __attribute__((ext_vector_type(8))) short    s8v;   // 8 x bf16
typedef __attribute__((ext_vector_type(4))) float    f4v;   // MFMA acc
typedef __attribute__((ext_vector_type(2))) unsigned u2v;   // packed 4 x bf16

// ---- workspace layout (bytes) ----
#define OFF_X0  0ull
#define SZ_X0   ((unsigned long long)TST * 64 * Hdim * 2ull)   // bf16 X0
#define OFF_HB  (OFF_X0 + SZ_X0)                                // h    [64][1024] bf16
#define OFF_N1  (OFF_HB + 131072ull)
#define OFF_N3  (OFF_N1 + 131072ull)
#define OFF_N5  (OFF_N3 + 131072ull)
#define OFF_N2  (OFF_N5 + 131072ull)
#define OFF_N4  (OFF_N2 + 131072ull)
#define OFF_W0B (OFF_N4 + 131072ull)                            // bf16 W0 2 MB
#define OFF_FLG (OFF_W0B + 2097152ull)                          // 6 groups x 64 wave-flags
#define WS_NEED (OFF_FLG + 4096ull)

__device__ __forceinline__ unsigned short f2b(float f) {
  union { float f; unsigned u; } v; v.f = f;
  return (unsigned short)((v.u + 0x7FFFu + ((v.u >> 16) & 1u)) >> 16);  // RNE
}
__device__ __forceinline__ float b2f(unsigned short u) {
  union { unsigned u; float f; } v; v.u = ((unsigned)u) << 16;
  return v.f;
}
__device__ __forceinline__ float fast_tanh(float x) { return 1.f - 2.f / (__expf(2.f * x) + 1.f); }
__device__ __forceinline__ float fast_sigm(float x) { return 1.f / (1.f + __expf(-x)); }
__device__ __forceinline__ s8v pack8(const float* __restrict__ p) {
  s8v r;
#pragma unroll
  for (int i = 0; i < 8; ++i) r[i] = (short)f2b(p[i]);
  return r;
}

// ---- coherent (L3-direct) helpers ----
__device__ __forceinline__ void st_sc1_u32(unsigned* p, unsigned v) {
  asm volatile("global_store_dword %0, %1, off sc0 sc1" :: "v"(p), "v"(v) : "memory");
}
__device__ __forceinline__ void st_sc1_64(unsigned short* p, u2v v) {
  asm volatile("global_store_dwordx2 %0, %1, off sc0 sc1" :: "v"(p), "v"(v) : "memory");
}
__device__ __forceinline__ void wait_vm0() { asm volatile("s_waitcnt vmcnt(0)" ::: "memory"); }
__device__ __forceinline__ void st_bf4(unsigned short* p, float x0, float x1, float x2, float x3) {
  u2v v;
  v[0] = (unsigned)f2b(x0) | ((unsigned)f2b(x1) << 16);
  v[1] = (unsigned)f2b(x2) | ((unsigned)f2b(x3) << 16);
  st_sc1_64(p, v);
}

// per-wave flag polls: lane i checks flag i of a 64-flag group. One load + drain
// per iteration, all in ONE asm block (R3 lesson).
__device__ __forceinline__ void poll1(const unsigned* base, unsigned tgt) {
  const unsigned* p = base + (threadIdx.x & 63);
  int gd = 0;
  for (;;) {
    unsigned v;
    asm volatile("global_load_dword %0, %1, off sc0 sc1\n\ts_waitcnt vmcnt(0)"
                 : "=v"(v) : "v"(p) : "memory");
    if (__all((int)(v >= tgt))) break;
    if (++gd >= POLL_GUARD) break;
  }
}
__device__ __forceinline__ void poll3(const unsigned* b1, const unsigned* b2,
                                      const unsigned* b3, unsigned tgt) {
  const int l = threadIdx.x & 63;
  const unsigned *p1 = b1 + l, *p2 = b2 + l, *p3 = b3 + l;
  int gd = 0;
  for (;;) {
    unsigned v1, v2, v3;
    asm volatile("global_load_dword %0, %3, off sc0 sc1\n\t"
                 "global_load_dword %1, %4, off sc0 sc1\n\t"
                 "global_load_dword %2, %5, off sc0 sc1\n\t"
                 "s_waitcnt vmcnt(0)"
                 : "=&v"(v1), "=&v"(v2), "=&v"(v3)
                 : "v"(p1), "v"(p2), "v"(p3) : "memory");
    if (__all((int)((v1 >= tgt) & (v2 >= tgt) & (v3 >= tgt)))) break;
    if (++gd >= POLL_GUARD) break;
  }
}

// 16 sc1 dwordx4 loads + drain in ONE asm block (proven shape, 17 operands)
#define GL16(B, P) asm volatile(                                        \
  "global_load_dwordx4 %0,  %16, off sc0 sc1\n\t"                       \
  "global_load_dwordx4 %1,  %16, off offset:64 sc0 sc1\n\t"             \
  "global_load_dwordx4 %2,  %16, off offset:128 sc0 sc1\n\t"            \
  "global_load_dwordx4 %3,  %16, off offset:192 sc0 sc1\n\t"            \
  "global_load_dwordx4 %4,  %16, off offset:256 sc0 sc1\n\t"            \
  "global_load_dwordx4 %5,  %16, off offset:320 sc0 sc1\n\t"            \
  "global_load_dwordx4 %6,  %16, off offset:384 sc0 sc1\n\t"            \
  "global_load_dwordx4 %7,  %16, off offset:448 sc0 sc1\n\t"            \
  "global_load_dwordx4 %8,  %16, off offset:512 sc0 sc1\n\t"            \
  "global_load_dwordx4 %9,  %16, off offset:576 sc0 sc1\n\t"            \
  "global_load_dwordx4 %10, %16, off offset:640 sc0 sc1\n\t"            \
  "global_load_dwordx4 %11, %16, off offset:704 sc0 sc1\n\t"            \
  "global_load_dwordx4 %12, %16, off offset:768 sc0 sc1\n\t"            \
  "global_load_dwordx4 %13, %16, off offset:832 sc0 sc1\n\t"            \
  "global_load_dwordx4 %14, %16, off offset:896 sc0 sc1\n\t"            \
  "global_load_dwordx4 %15, %16, off offset:960 sc0 sc1\n\t"            \
  "s_waitcnt vmcnt(0)"                                                  \
  : "=&v"(B[0]), "=&v"(B[1]), "=&v"(B[2]), "=&v"(B[3]),                 \
    "=&v"(B[4]), "=&v"(B[5]), "=&v"(B[6]), "=&v"(B[7]),                 \
    "=&v"(B[8]), "=&v"(B[9]), "=&v"(B[10]), "=&v"(B[11]),               \
    "=&v"(B[12]), "=&v"(B[13]), "=&v"(B[14]), "=&v"(B[15])              \
  : "v"(P) : "memory")

// 8 dwordx2 leaf loads (n2,n4) + drain, self-contained (10 operands)
__device__ __forceinline__ void ld_leaf8(const unsigned short* p2,
                                         const unsigned short* p4,
                                         u2v L2v[4], u2v L4v[4]) {
  asm volatile(
    "global_load_dwordx2 %0, %8, off sc0 sc1\n\t"
    "global_load_dwordx2 %1, %8, off offset:32 sc0 sc1\n\t"
    "global_load_dwordx2 %2, %8, off offset:64 sc0 sc1\n\t"
    "global_load_dwordx2 %3, %8, off offset:96 sc0 sc1\n\t"
    "global_load_dwordx2 %4, %9, off sc0 sc1\n\t"
    "global_load_dwordx2 %5, %9, off offset:32 sc0 sc1\n\t"
    "global_load_dwordx2 %6, %9, off offset:64 sc0 sc1\n\t"
    "global_load_dwordx2 %7, %9, off offset:96 sc0 sc1\n\t"
    "s_waitcnt vmcnt(0)"
    : "=&v"(L2v[0]), "=&v"(L2v[1]), "=&v"(L2v[2]), "=&v"(L2v[3]),
      "=&v"(L4v[0]), "=&v"(L4v[1]), "=&v"(L4v[2]), "=&v"(L4v[3])
    : "v"(p2), "v"(p4) : "memory");
}

// ---------------- W0 fp32 -> bf16 ----------------
__global__ __launch_bounds__(256) void k_cvt(const float* __restrict__ src,
                                             unsigned short* __restrict__ dst) {
  const int i = (blockIdx.x * 256 + threadIdx.x) * 4;
  float4 v = *(const float4*)(src + i);
  ushort4 o; o.x = f2b(v.x); o.y = f2b(v.y); o.z = f2b(v.z); o.w = f2b(v.w);
  *(ushort4*)(dst + i) = o;
}

// ---------------- X0[t] = emb[idx[:,t+1]] @ W0^T + b0 + bs0, bf16 out ----------------
__global__ __launch_bounds__(256) void k_x0(const float* __restrict__ emb,
                                            const int* __restrict__ ids,
                                            const unsigned short* __restrict__ w0b,
                                            const float* __restrict__ b0,
                                            const float* __restrict__ bs,
                                            unsigned short* __restrict__ x0b) {
  const int t  = blockIdx.x;            // 0..126
  const int cb = blockIdx.y * 256;
  const int lane = threadIdx.x & 63, wvv = threadIdx.x >> 6;
  const int lc = lane & 15, lg = lane >> 4;
  const int cw = cb + wvv * 64;
  const float* erow[4];
#pragma unroll
  for (int rt = 0; rt < 4; ++rt)
    erow[rt] = emb + (size_t)ids[(rt * 16 + lc) * 128 + t + 1] * Hdim + lg * 8;
  f4v acc[4][4];   // [ct][rt]
#pragma unroll
  for (int ct = 0; ct < 4; ++ct)
#pragma unroll
    for (int rt = 0; rt < 4; ++rt) acc[ct][rt] = (f4v){0.f, 0.f, 0.f, 0.f};

  for (int ks = 0; ks < 32; ++ks) {
    s8v bf[4];
#pragma unroll
    for (int rt = 0; rt < 4; ++rt) bf[rt] = pack8(erow[rt] + ks * 32);
#pragma unroll
    for (int ct = 0; ct < 4; ++ct) {
      s8v a = *(const s8v*)(w0b + (size_t)(cw + ct * 16 + lc) * Hdim + ks * 32 + lg * 8);
#pragma unroll
      for (int rt = 0; rt < 4; ++rt)
        acc[ct][rt] = __builtin_amdgcn_mfma_f32_16x16x32_bf16(a, bf[rt], acc[ct][rt], 0, 0, 0);
    }
  }
  unsigned short* xt = x0b + (size_t)t * (64 * Hdim);
#pragma unroll
  for (int ct = 0; ct < 4; ++ct) {
    const int colq = cw + ct * 16 + lg * 4;
    float4 bias = *(const float4*)(b0 + colq);
    float4 bsv  = *(const float4*)(bs + colq);     // bs row 0
#pragma unroll
    for (int rt = 0; rt < 4; ++rt) {
      const int row = rt * 16 + lc;
      ushort4 o;
      o.x = f2b(acc[ct][rt][0] + bias.x + bsv.x);
      o.y = f2b(acc[ct][rt][1] + bias.y + bsv.y);
      o.z = f2b(acc[ct][rt][2] + bias.z + bsv.z);
      o.w = f2b(acc[ct][rt][3] + bias.w + bsv.w);
      *(ushort4*)(xt + (size_t)row * Hdim + colq) = o;
    }
  }
}

// 64-row x 64-col GEMM slice per WG: acc[ct] = D tile ct. Transposed MFMA:
// lane(lc,lg) of wave wvv: act row = wvv*16+lc, W cols = c0+ct*16+lg*4+0..3.
__device__ __forceinline__ void gemm64(const unsigned short* in_b,
                                       const unsigned short* ldsW,
                                       int lc, int lg, int wvv, f4v acc[4]) {
  const unsigned short* pa = in_b + (size_t)(wvv * 16 + lc) * Hdim + lg * 8;
  const unsigned short* br = ldsW + lg * 512 + lc * 8;
  s8v bb[16];
  GL16(bb, pa);
  __builtin_amdgcn_sched_barrier(0);
#pragma unroll
  for (int k = 0; k < 16; ++k)
#pragma unroll
    for (int ct = 0; ct < 4; ++ct)
      acc[ct] = __builtin_amdgcn_mfma_f32_16x16x32_bf16(
          *(const s8v*)(br + k * 2048 + ct * 128), bb[k], acc[ct], 0, 0, 0);
  GL16(bb, pa + 512);
  __builtin_amdgcn_sched_barrier(0);
#pragma unroll
  for (int k = 0; k < 16; ++k)
#pragma unroll
    for (int ct = 0; ct < 4; ++ct)
      acc[ct] = __builtin_amdgcn_mfma_f32_16x16x32_bf16(
          *(const s8v*)(br + (16 + k) * 2048 + ct * 128), bb[k], acc[ct], 0, 0, 0);
}

// ---------------- persistent scan: 6 DAG groups x 16 col-tiles ----------------
__global__ __launch_bounds__(256, 1) void k_scan(const float* __restrict__ Ws,
                                                 const float* __restrict__ bs,
                                                 const float* __restrict__ h_in,
                                                 const float* __restrict__ Wsum,
                                                 const float* __restrict__ bsum,
                                                 const float* __restrict__ act,
                                                 char* __restrict__ ws) {
  __shared__ unsigned short ldsW[65536];   // exactly 128 KiB (m201-proven size)
  const int tid = threadIdx.x;
  const int lane = tid & 63, wvv = tid >> 6;
  const int lc = lane & 15, lg = lane >> 4;
  const int g = blockIdx.x >> 4;           // group 0..5 owns matrix M_g
  const int tile = blockIdx.x & 15;
  const int c0 = tile * 64;

  unsigned* flg = (unsigned*)(ws + OFF_FLG);             // [6][64] per-wave flags
  unsigned short* hb  = (unsigned short*)(ws + OFF_HB);
  unsigned short* n1b = (unsigned short*)(ws + OFF_N1);
  unsigned short* n3b = (unsigned short*)(ws + OFF_N3);
  unsigned short* n5b = (unsigned short*)(ws + OFF_N5);
  unsigned short* n2b = (unsigned short*)(ws + OFF_N2);
  unsigned short* n4b = (unsigned short*)(ws + OFF_N4);
  const unsigned short* x0b = (const unsigned short*)(ws + OFF_X0);

  // LDS: matrix g cols [c0, c0+64), tiled [k/8][64][8]
  for (int idx = tid; idx < 16384; idx += 256) {
    const int c = idx >> 8, k4 = idx & 255;
    float4 v = *(const float4*)(Ws + (size_t)g * (Hdim * Hdim) + (size_t)(c0 + c) * Hdim + k4 * 4);
    ushort4 o; o.x = f2b(v.x); o.y = f2b(v.y); o.z = f2b(v.z); o.w = f2b(v.w);
    *(ushort4*)(ldsW + ((size_t)(k4 >> 1) * 64 + c) * 8 + (k4 & 1) * 4) = o;
  }
  // per-lane bias: 4 cols per col-tile (none for g0 -- baked into X0)
  float4 bias[4];
#pragma unroll
  for (int ct = 0; ct < 4; ++ct)
    bias[ct] = (g >= 1) ? *(const float4*)(bs + (size_t)g * Hdim + c0 + ct * 16 + lg * 4)
                        : (float4){0.f, 0.f, 0.f, 0.f};
  // softmax combine weights (G5 only uses them)
  float cw0, cw1, cw2;
  {
    float c[3];
#pragma unroll
    for (int j = 0; j < 3; ++j) {
      const int i = 2 * j + 1;
      float s = bsum[i];
      for (int a2 = 0; a2 < 12; ++a2) s += Wsum[i * 12 + a2] * act[a2];
      c[j] = s;
    }
    float m = fmaxf(c[0], fmaxf(c[1], c[2]));
    float e0 = __expf(c[0] - m), e1 = __expf(c[1] - m), e2 = __expf(c[2] - m);
    float inv = 1.f / (e0 + e1 + e2);
    cw0 = e0 * inv; cw1 = e1 * inv; cw2 = e2 * inv;
  }
  __syncthreads();                          // LDS ready

  const int row = wvv * 16 + lc;
  unsigned* wf = flg + g * 64 + tile * 4 + wvv;   // this wave's flag (sole writer)
  const unsigned *f0 = flg, *f2 = flg + 2 * 64, *f5 = flg + 5 * 64;
  const unsigned *f1 = flg + 1 * 64, *f3 = flg + 3 * 64, *f4g = flg + 4 * 64;

  if (g == 5) {
    // pre-loop: publish h(0) = bf16(h_in), flag value 1
    for (int e = tid; e < 2048; e += 256) {
      const int r = e >> 5, c2 = (e & 31) * 2;
      const float* hp = h_in + (size_t)r * Hdim + c0 + c2;
      unsigned pk = (unsigned)f2b(hp[0]) | ((unsigned)f2b(hp[1]) << 16);
      st_sc1_u32((unsigned*)(hb + (size_t)r * Hdim + c0 + c2), pk);
    }
    wait_vm0();
    __syncthreads();
    if (lane == 0) st_sc1_u32(wf, 1u);
  }

  if (g == 0) {            // n1 = tanh(M0 h + X0[t])
    for (int t = 0; t < TST; ++t) {
      poll1(f5, (unsigned)t + 1u);
      ushort4 xu[4];
      const unsigned short* xt = x0b + (size_t)t * 65536 + (size_t)row * Hdim + c0 + lg * 4;
#pragma unroll
      for (int ct = 0; ct < 4; ++ct) xu[ct] = *(const ushort4*)(xt + ct * 16);
      f4v acc[4] = {{0.f,0.f,0.f,0.f},{0.f,0.f,0.f,0.f},{0.f,0.f,0.f,0.f},{0.f,0.f,0.f,0.f}};
      gemm64(hb, ldsW, lc, lg, wvv, acc);
#pragma unroll
      for (int ct = 0; ct < 4; ++ct)
        st_bf4(n1b + (size_t)row * Hdim + c0 + ct * 16 + lg * 4,
               fast_tanh(acc[ct][0] + b2f(xu[ct].x)), fast_tanh(acc[ct][1] + b2f(xu[ct].y)),
               fast_tanh(acc[ct][2] + b2f(xu[ct].z)), fast_tanh(acc[ct][3] + b2f(xu[ct].w)));
      wait_vm0();
      if (lane == 0) st_sc1_u32(wf, (unsigned)t + 1u);
    }
  } else if (g == 1) {     // n2 = relu(M1 n1 + b1)
    for (int t = 0; t < TST; ++t) {
      poll1(f0, (unsigned)t + 1u);
      f4v acc[4] = {{0.f,0.f,0.f,0.f},{0.f,0.f,0.f,0.f},{0.f,0.f,0.f,0.f},{0.f,0.f,0.f,0.f}};
      gemm64(n1b, ldsW, lc, lg, wvv, acc);
#pragma unroll
      for (int ct = 0; ct < 4; ++ct)
        st_bf4(n2b + (size_t)row * Hdim + c0 + ct * 16 + lg * 4,
               fmaxf(acc[ct][0] + bias[ct].x, 0.f), fmaxf(acc[ct][1] + bias[ct].y, 0.f),
               fmaxf(acc[ct][2] + bias[ct].z, 0.f), fmaxf(acc[ct][3] + bias[ct].w, 0.f));
      wait_vm0();
      if (lane == 0) st_sc1_u32(wf, (unsigned)t + 1u);
    }
  } else if (g == 2) {     // n3 = sigmoid(M2 n1 + b2)
    for (int t = 0; t < TST; ++t) {
      poll1(f0, (unsigned)t + 1u);
      f4v acc[4] = {{0.f,0.f,0.f,0.f},{0.f,0.f,0.f,0.f},{0.f,0.f,0.f,0.f},{0.f,0.f,0.f,0.f}};
      gemm64(n1b, ldsW, lc, lg, wvv, acc);
#pragma unroll
      for (int ct = 0; ct < 4; ++ct)
        st_bf4(n3b + (size_t)row * Hdim + c0 + ct * 16 + lg * 4,
               fast_sigm(acc[ct][0] + bias[ct].x), fast_sigm(acc[ct][1] + bias[ct].y),
               fast_sigm(acc[ct][2] + bias[ct].z), fast_sigm(acc[ct][3] + bias[ct].w));
      wait_vm0();
      if (lane == 0) st_sc1_u32(wf, (unsigned)t + 1u);
    }
  } else if (g == 3) {     // n4 = tanh(M3 n3 + b3)
    for (int t = 0; t < TST; ++t) {
      poll1(f2, (unsigned)t + 1u);
      f4v acc[4] = {{0.f,0.f,0.f,0.f},{0.f,0.f,0.f,0.f},{0.f,0.f,0.f,0.f},{0.f,0.f,0.f,0.f}};
      gemm64(n3b, ldsW, lc, lg, wvv, acc);
#pragma unroll
      for (int ct = 0; ct < 4; ++ct)
        st_bf4(n4b + (size_t)row * Hdim + c0 + ct * 16 + lg * 4,
               fast_tanh(acc[ct][0] + bias[ct].x), fast_tanh(acc[ct][1] + bias[ct].y),
               fast_tanh(acc[ct][2] + bias[ct].z), fast_tanh(acc[ct][3] + bias[ct].w));
      wait_vm0();
      if (lane == 0) st_sc1_u32(wf, (unsigned)t + 1u);
    }
  } else if (g == 4) {     // n5 = relu(M4 n3 + b4)
    for (int t = 0; t < TST; ++t) {
      poll1(f2, (unsigned)t + 1u);
      f4v acc[4] = {{0.f,0.f,0.f,0.f},{0.f,0.f,0.f,0.f},{0.f,0.f,0.f,0.f},{0.f,0.f,0.f,0.f}};
      gemm64(n3b, ldsW, lc, lg, wvv, acc);
#pragma unroll
      for (int ct = 0; ct < 4; ++ct)
        st_bf4(n5b + (size_t)row * Hdim + c0 + ct * 16 + lg * 4,
               fmaxf(acc[ct][0] + bias[ct].x, 0.f), fmaxf(acc[ct][1] + bias[ct].y, 0.f),
               fmaxf(acc[ct][2] + bias[ct].z, 0.f), fmaxf(acc[ct][3] + bias[ct].w, 0.f));
      wait_vm0();
      if (lane == 0) st_sc1_u32(wf, (unsigned)t + 1u);
    }
  } else {                 // g == 5: n6 = tanh(M5 n5 + b5); h' = combine(n2, n4, n6)
    for (int t = 0; t < TST; ++t) {
      poll3(f1, f3, f4g, (unsigned)t + 1u);
      u2v L2v[4], L4v[4];
      ld_leaf8(n2b + (size_t)row * Hdim + c0 + lg * 4,
               n4b + (size_t)row * Hdim + c0 + lg * 4, L2v, L4v);
      f4v acc[4] = {{0.f,0.f,0.f,0.f},{0.f,0.f,0.f,0.f},{0.f,0.f,0.f,0.f},{0.f,0.f,0.f,0.f}};
      gemm64(n5b, ldsW, lc, lg, wvv, acc);
#pragma unroll
      for (int ct = 0; ct < 4; ++ct) {
        float hv[4];
#pragma unroll
        for (int j = 0; j < 4; ++j) {
          const float n6j = fast_tanh(acc[ct][j] + ((const float*)&bias[ct])[j]);
          const float n2j = b2f((unsigned short)(L2v[ct][j >> 1] >> ((j & 1) * 16)));
          const float n4j = b2f((unsigned short)(L4v[ct][j >> 1] >> ((j & 1) * 16)));
          hv[j] = cw0 * n2j + cw1 * n4j + cw2 * n6j;
        }
        st_bf4(hb + (size_t)row * Hdim + c0 + ct * 16 + lg * 4, hv[0], hv[1], hv[2], hv[3]);
      }
      wait_vm0();
      if (lane == 0) st_sc1_u32(wf, (unsigned)t + 2u);   // h(t+1) available
    }
  }
}

// ---------------- epilogue: out = h @ W_out^T + b_out ----------------
__global__ __launch_bounds__(256) void k_out(const unsigned short* __restrict__ hb,
                                             const float* __restrict__ wout,
                                             const float* __restrict__ bout,
                                             float* __restrict__ out) {
  const int cb = blockIdx.x * 128;
  const int lane = threadIdx.x & 63, wvv = threadIdx.x >> 6;
  const int lc = lane & 15, lg = lane >> 4;
  const int cw = cb + wvv * 32;
  f4v acc[4][2];
#pragma unroll
  for (int rt = 0; rt < 4; ++rt)
#pragma unroll
    for (int ct = 0; ct < 2; ++ct) acc[rt][ct] = (f4v){0.f, 0.f, 0.f, 0.f};

  for (int ks = 0; ks < 32; ++ks) {
    s8v a[4];
#pragma unroll
    for (int rt = 0; rt < 4; ++rt)
      a[rt] = *(const s8v*)(hb + (rt * 16 + lc) * Hdim + ks * 32 + lg * 8);
#pragma unroll
    for (int ct = 0; ct < 2; ++ct) {
      const int col = cw + ct * 16 + lc;
      const int cs = col < NCLS ? col : NCLS - 1;
      s8v b = pack8(wout + (size_t)cs * Hdim + ks * 32 + lg * 8);
#pragma unroll
      for (int rt = 0; rt < 4; ++rt)
        acc[rt][ct] = __builtin_amdgcn_mfma_f32_16x16x32_bf16(a[rt], b, acc[rt][ct], 0, 0, 0);
    }
  }
#pragma unroll
  for (int ct = 0; ct < 2; ++ct) {
    const int col = cw + ct * 16 + lc;
    if (col < NCLS) {
      const float bias = bout[col];
#pragma unroll
      for (int rt = 0; rt < 4; ++rt)
#pragma unroll
        for (int j = 0; j < 4; ++j)
          out[(size_t)(rt * 16 + lg * 4 + j) * NCLS + col] = acc[rt][ct][j] + bias;
    }
  }
}

extern "C" void kernel_launch(void* const* d_in, const int* in_sizes, int n_in,
                              void* d_out, int out_size, void* d_ws, size_t ws_size,
                              hipStream_t stream) {
  (void)in_sizes; (void)n_in; (void)out_size;
  if (ws_size < WS_NEED) return;

  const float* emb  = (const float*)d_in[0];
  const float* h0   = (const float*)d_in[1];
  const int*   ids  = (const int*)d_in[2];
  const float* W0   = (const float*)d_in[3];
  const float* b0   = (const float*)d_in[4];
  const float* Ws   = (const float*)d_in[5];
  const float* bsp  = (const float*)d_in[6];
  const float* Wout = (const float*)d_in[7];
  const float* bout = (const float*)d_in[8];
  const float* Wsum = (const float*)d_in[9];
  const float* bsum = (const float*)d_in[10];
  const float* actv = (const float*)d_in[11];
  char* ws  = (char*)d_ws;
  float* out = (float*)d_out;

  hipMemsetAsync(ws + OFF_FLG, 0, 4096, stream);                      // flags
  k_cvt<<<1024, 256, 0, stream>>>(W0, (unsigned short*)(ws + OFF_W0B));
  k_x0<<<dim3(TST, 4), 256, 0, stream>>>(emb, ids, (const unsigned short*)(ws + OFF_W0B),
                                         b0, bsp, (unsigned short*)(ws + OFF_X0));

  void* args[] = { (void*)&Ws, (void*)&bsp, (void*)&h0, (void*)&Wsum,
                   (void*)&bsum, (void*)&actv, (void*)&ws };
  hipError_t e = hipLaunchCooperativeKernel((void*)k_scan, dim3(NWG), dim3(256), args, 0, stream);
  if (e != hipSuccess) {
    // validation-path fallback: 96 WGs at 1/CU on 256 CUs are de-facto co-resident;
    // all polls are guarded, so worst case is a wrong answer, never a hang.
    k_scan<<<dim3(NWG), dim3(256), 0, stream>>>(Ws, bsp, h0, Wsum, bsum, actv, ws);
  }

  k_out<<<391, 256, 0, stream>>>((const unsigned short*)(ws + OFF_HB), Wout, bout, out);
}

// Round 11
// 1982.572 us; speedup vs baseline: 6.8774x; 2.5315x over previous
//
#include <hip/hip_runtime.h>
#include <hip/hip_bf16.h>

#define Hdim 1024
#define TST  127
#define NCLS 50000
#define POLL_GUARD (1 << 17)

typedef __attribute__((ext_vector_type(8))) short    s8v;   // 8 x bf16
typedef __attribute__((ext_vector_type(4))) float    f4v;   // MFMA acc
typedef __attribute__((ext_vector_type(2))) unsigned u2v;   // packed 4 x bf16

// ---- workspace layout (bytes) ----
#define OFF_X0   0ull
#define SZ_X0    ((unsigned long long)TST * 64 * Hdim * 2ull)   // 16,646,144 bf16 X0
#define OFF_W0B  (OFF_X0 + SZ_X0)                                // 2 MB bf16 embedding W0
#define OFF_WSB  (OFF_W0B + 2097152ull)                          // 12 MB bf16 Ws[6]
#define OFF_ACT  (OFF_WSB + 12582912ull)                         // 8 xcd x 4 bufs x 16 KB
#define OFF_HB   (OFF_ACT + 524288ull)                           // final h [64][1024] bf16
#define OFF_FLG  (OFF_HB + 131072ull)                            // flags[8][6][32] + ranks[8]
#define WS_NEED  (OFF_FLG + 8192ull)

__device__ __forceinline__ unsigned short f2b(float f) {
  union { float f; unsigned u; } v; v.f = f;
  return (unsigned short)((v.u + 0x7FFFu + ((v.u >> 16) & 1u)) >> 16);  // RNE
}
__device__ __forceinline__ float b2f(unsigned short u) {
  union { unsigned u; float f; } v; v.u = ((unsigned)u) << 16;
  return v.f;
}
__device__ __forceinline__ float fast_tanh(float x) { return 1.f - 2.f / (__expf(2.f * x) + 1.f); }
__device__ __forceinline__ float fast_sigm(float x) { return 1.f / (1.f + __expf(-x)); }
__device__ __forceinline__ s8v pack8(const float* __restrict__ p) {
  s8v r;
#pragma unroll
  for (int i = 0; i < 8; ++i) r[i] = (short)f2b(p[i]);
  return r;
}
__device__ __forceinline__ u2v pk4(float a, float b, float c, float d) {
  u2v v;
  v[0] = (unsigned)f2b(a) | ((unsigned)f2b(b) << 16);
  v[1] = (unsigned)f2b(c) | ((unsigned)f2b(d) << 16);
  return v;
}

// ---- access helpers: sc1 = L3 coherence point; sc0 = L1-bypass, own-XCD L2 ----
__device__ __forceinline__ void st_sc1_u32(unsigned* p, unsigned v) {
  asm volatile("global_store_dword %0, %1, off sc0 sc1" :: "v"(p), "v"(v) : "memory");
}
__device__ __forceinline__ void st_sc0_u32(unsigned* p, unsigned v) {
  asm volatile("global_store_dword %0, %1, off sc0" :: "v"(p), "v"(v) : "memory");
}
__device__ __forceinline__ void st_sc0_64(unsigned short* p, u2v v) {
  asm volatile("global_store_dwordx2 %0, %1, off sc0" :: "v"(p), "v"(v) : "memory");
}
__device__ __forceinline__ void wait_vm0() { asm volatile("s_waitcnt vmcnt(0)" ::: "memory"); }

// poll 32 flags (lane & 31) >= tgt; one sc1 load + drain per iter (R3 lesson: one block)
__device__ __forceinline__ void pollg(const unsigned* fb, unsigned tgt) {
  const unsigned* p = fb + (threadIdx.x & 31);
  int gd = 0;
  for (;;) {
    unsigned v;
    asm volatile("global_load_dword %0, %1, off sc0 sc1\n\ts_waitcnt vmcnt(0)"
                 : "=v"(v) : "v"(p) : "memory");
    if (__all((int)(v >= tgt))) break;
    if (++gd >= POLL_GUARD) break;
  }
}

// 8 sc0 dwordx4 act loads + drain in ONE asm block (9 operands, proven scale)
#define GL8S0(B, P) asm volatile(                                       \
  "global_load_dwordx4 %0, %8, off sc0\n\t"                             \
  "global_load_dwordx4 %1, %8, off offset:64 sc0\n\t"                   \
  "global_load_dwordx4 %2, %8, off offset:128 sc0\n\t"                  \
  "global_load_dwordx4 %3, %8, off offset:192 sc0\n\t"                  \
  "global_load_dwordx4 %4, %8, off offset:256 sc0\n\t"                  \
  "global_load_dwordx4 %5, %8, off offset:320 sc0\n\t"                  \
  "global_load_dwordx4 %6, %8, off offset:384 sc0\n\t"                  \
  "global_load_dwordx4 %7, %8, off offset:448 sc0\n\t"                  \
  "s_waitcnt vmcnt(0)"                                                  \
  : "=&v"(B[0]), "=&v"(B[1]), "=&v"(B[2]), "=&v"(B[3]),                 \
    "=&v"(B[4]), "=&v"(B[5]), "=&v"(B[6]), "=&v"(B[7])                  \
  : "v"(P) : "memory")

// ---------------- fp32 -> bf16 bulk convert (W0 and Ws) ----------------
__global__ __launch_bounds__(256) void k_cvt(const float* __restrict__ src,
                                             unsigned short* __restrict__ dst) {
  const int i = (blockIdx.x * 256 + threadIdx.x) * 4;
  float4 v = *(const float4*)(src + i);
  ushort4 o; o.x = f2b(v.x); o.y = f2b(v.y); o.z = f2b(v.z); o.w = f2b(v.w);
  *(ushort4*)(dst + i) = o;
}

// ---------------- X0[t] = emb[idx[:,t+1]] @ W0^T + b0 + bs0, bf16 out ----------------
__global__ __launch_bounds__(256) void k_x0(const float* __restrict__ emb,
                                            const int* __restrict__ ids,
                                            const unsigned short* __restrict__ w0b,
                                            const float* __restrict__ b0,
                                            const float* __restrict__ bs,
                                            unsigned short* __restrict__ x0b) {
  const int t  = blockIdx.x;            // 0..126
  const int cb = blockIdx.y * 256;
  const int lane = threadIdx.x & 63, wvv = threadIdx.x >> 6;
  const int lc = lane & 15, lg = lane >> 4;
  const int cw = cb + wvv * 64;
  const float* erow[4];
#pragma unroll
  for (int rt = 0; rt < 4; ++rt)
    erow[rt] = emb + (size_t)ids[(rt * 16 + lc) * 128 + t + 1] * Hdim + lg * 8;
  f4v acc[4][4];   // [ct][rt]
#pragma unroll
  for (int ct = 0; ct < 4; ++ct)
#pragma unroll
    for (int rt = 0; rt < 4; ++rt) acc[ct][rt] = (f4v){0.f, 0.f, 0.f, 0.f};

  for (int ks = 0; ks < 32; ++ks) {
    s8v bf[4];
#pragma unroll
    for (int rt = 0; rt < 4; ++rt) bf[rt] = pack8(erow[rt] + ks * 32);
#pragma unroll
    for (int ct = 0; ct < 4; ++ct) {
      s8v a = *(const s8v*)(w0b + (size_t)(cw + ct * 16 + lc) * Hdim + ks * 32 + lg * 8);
#pragma unroll
      for (int rt = 0; rt < 4; ++rt)
        acc[ct][rt] = __builtin_amdgcn_mfma_f32_16x16x32_bf16(a, bf[rt], acc[ct][rt], 0, 0, 0);
    }
  }
  unsigned short* xt = x0b + (size_t)t * (64 * Hdim);
#pragma unroll
  for (int ct = 0; ct < 4; ++ct) {
    const int colq = cw + ct * 16 + lg * 4;
    float4 bias = *(const float4*)(b0 + colq);
    float4 bsv  = *(const float4*)(bs + colq);     // bs row 0
#pragma unroll
    for (int rt = 0; rt < 4; ++rt) {
      const int row = rt * 16 + lc;
      ushort4 o;
      o.x = f2b(acc[ct][rt][0] + bias.x + bsv.x);
      o.y = f2b(acc[ct][rt][1] + bias.y + bsv.y);
      o.z = f2b(acc[ct][rt][2] + bias.z + bsv.z);
      o.w = f2b(acc[ct][rt][3] + bias.w + bsv.w);
      *(ushort4*)(xt + (size_t)row * Hdim + colq) = o;
    }
  }
}

// ---------------- persistent scan: 8 independent XCD-local row chains ----------------
__global__ __launch_bounds__(256, 1) void k_scan(const float* __restrict__ bs,
                                                 const float* __restrict__ h_in,
                                                 const float* __restrict__ Wsum,
                                                 const float* __restrict__ bsum,
                                                 const float* __restrict__ act,
                                                 char* __restrict__ ws) {
  __shared__ float part[2][4][8][32];    // 8 KB: per-wave partial sums, 2 matrices
  __shared__ float n2l[8][32];           // 1 KB: n2 leaf (WG-local)
  __shared__ float n4l[8][32];           // 1 KB: n4 leaf
  __shared__ char  pad_lds[81920];       // 80 KB: forces 1 WG/CU -> exactly 32 WG/XCD
  __shared__ int   s_info[2];

  const int tid = threadIdx.x;
  pad_lds[tid] = (char)tid;              // keep pad allocated
  asm volatile("" :: "v"((int)pad_lds[tid]));

  const int lane = tid & 63, wv = tid >> 6;
  const int lc = lane & 15, lg = lane >> 4;
  const int lr = lc & 7;                 // act row (rows 8..15 duplicate 0..7)

  unsigned* flg_all = (unsigned*)(ws + OFF_FLG);
  unsigned* ranks   = flg_all + 1536;

  if (tid == 0) {
    unsigned x;
    asm volatile("s_getreg_b32 %0, hwreg(HW_REG_XCC_ID)" : "=s"(x));
    x &= 7u;
    unsigned rr = __hip_atomic_fetch_add(&ranks[x], 1u, __ATOMIC_RELAXED, __HIP_MEMORY_SCOPE_AGENT);
    s_info[0] = (int)x; s_info[1] = (int)rr;
  }
  __syncthreads();
  const int xcd = s_info[0];
  const int r   = s_info[1];
  if (r >= 32) return;                   // impossible by pigeonhole (1 WG/CU); guard anyway
  const int c0w = r * 32;

  unsigned short* actX = (unsigned short*)(ws + OFF_ACT) + (size_t)xcd * 32768;
  unsigned short* hL  = actX;            // [8][1024] bf16 per buffer
  unsigned short* n1L = actX + 8192;
  unsigned short* n3L = actX + 16384;
  unsigned short* n5L = actX + 24576;
  unsigned* flgX = flg_all + xcd * 192;  // [6][32]
  unsigned* fg0 = flgX;                  // n1
  unsigned* fg2 = flgX + 64;             // n3
  unsigned* fg4 = flgX + 128;            // n5
  unsigned* fg5 = flgX + 160;            // h
  const unsigned short* wsb = (const unsigned short*)(ws + OFF_WSB);
  const unsigned short* x0b = (const unsigned short*)(ws + OFF_X0);
  unsigned short* HB = (unsigned short*)(ws + OFF_HB);

  // softmax combine weights over leaves {2,4,6} -> Wsum rows {1,3,5}
  float cw0, cw1, cw2;
  {
    float c[3];
#pragma unroll
    for (int j = 0; j < 3; ++j) {
      const int i = 2 * j + 1;
      float s = bsum[i];
      for (int a2 = 0; a2 < 12; ++a2) s += Wsum[i * 12 + a2] * act[a2];
      c[j] = s;
    }
    float m = fmaxf(c[0], fmaxf(c[1], c[2]));
    float e0 = __expf(c[0] - m), e1 = __expf(c[1] - m), e2 = __expf(c[2] - m);
    float inv = 1.f / (e0 + e1 + e2);
    cw0 = e0 * inv; cw1 = e1 * inv; cw2 = e2 * inv;
  }

  // ---- preload resident weights Ws[1..5]: per wave 2 col-tiles x 8 k-chunks each ----
  const size_t wbase = (size_t)(c0w + lc) * Hdim + (size_t)wv * 256 + lg * 8;
  const size_t wct   = (size_t)16 * Hdim;
  s8v w1f[2][8], w2f[2][8], w3f[2][8], w4f[2][8], w5f[2][8];
#pragma unroll
  for (int i = 0; i < 8; ++i) {
    w1f[0][i] = *(const s8v*)(wsb + 1u * 1048576u + wbase + i * 32);
    w1f[1][i] = *(const s8v*)(wsb + 1u * 1048576u + wbase + wct + i * 32);
    w2f[0][i] = *(const s8v*)(wsb + 2u * 1048576u + wbase + i * 32);
    w2f[1][i] = *(const s8v*)(wsb + 2u * 1048576u + wbase + wct + i * 32);
    w3f[0][i] = *(const s8v*)(wsb + 3u * 1048576u + wbase + i * 32);
    w3f[1][i] = *(const s8v*)(wsb + 3u * 1048576u + wbase + wct + i * 32);
    w4f[0][i] = *(const s8v*)(wsb + 4u * 1048576u + wbase + i * 32);
    w4f[1][i] = *(const s8v*)(wsb + 4u * 1048576u + wbase + wct + i * 32);
    w5f[0][i] = *(const s8v*)(wsb + 5u * 1048576u + wbase + i * 32);
    w5f[1][i] = *(const s8v*)(wsb + 5u * 1048576u + wbase + wct + i * 32);
  }

  // ---- init: publish h(0) slice (sc0, own L2), flag g5 = 1 ----
  if (tid < 128) {
    const int row = tid >> 4, cp = (tid & 15) * 2;
    const float* hp = h_in + (size_t)(xcd * 8 + row) * Hdim + c0w + cp;
    unsigned pk = (unsigned)f2b(hp[0]) | ((unsigned)f2b(hp[1]) << 16);
    st_sc0_u32((unsigned*)(hL + (size_t)row * Hdim + c0w + cp), pk);
  }
  wait_vm0();
  __syncthreads();
  if (tid == 0) st_sc1_u32(fg5 + r, 1u);

  const f4v z4 = (f4v){0.f, 0.f, 0.f, 0.f};

  for (int t = 0; t < TST; ++t) {
    // ======== L1: n1 = tanh(Ws0 h + X0[t])  (Ws0 streamed) ========
    pollg(fg5, (unsigned)t + 1u);
    {
      s8v bb[8];
      GL8S0(bb, hL + (size_t)lr * Hdim + wv * 256 + lg * 8);
      unsigned long long w0a = (unsigned long long)wsb;
      asm volatile("" : "+v"(w0a));                  // launder: keep M0 loads in-loop
      const unsigned short* w0p = (const unsigned short*)w0a;
      f4v a0 = z4, a1 = z4;
#pragma unroll
      for (int i = 0; i < 8; ++i) {
        s8v wA = *(const s8v*)(w0p + wbase + i * 32);
        s8v wB = *(const s8v*)(w0p + wbase + wct + i * 32);
        a0 = __builtin_amdgcn_mfma_f32_16x16x32_bf16(wA, bb[i], a0, 0, 0, 0);
        a1 = __builtin_amdgcn_mfma_f32_16x16x32_bf16(wB, bb[i], a1, 0, 0, 0);
      }
      if (lc < 8) {
        *(f4v*)&part[0][wv][lc][lg * 4] = a0;
        *(f4v*)&part[0][wv][lc][16 + lg * 4] = a1;
      }
    }
    __syncthreads();
    if (wv == 0) {
      if (lc < 8) {
#pragma unroll
        for (int ct = 0; ct < 2; ++ct) {
          const int cb2 = ct * 16 + lg * 4;
          f4v s = *(f4v*)&part[0][0][lc][cb2] + *(f4v*)&part[0][1][lc][cb2]
                + *(f4v*)&part[0][2][lc][cb2] + *(f4v*)&part[0][3][lc][cb2];
          ushort4 xu = *(const ushort4*)(x0b + (size_t)t * 65536 +
                                         (size_t)(xcd * 8 + lc) * Hdim + c0w + cb2);
          st_sc0_64(n1L + (size_t)lc * Hdim + c0w + cb2,
                    pk4(fast_tanh(s[0] + b2f(xu.x)), fast_tanh(s[1] + b2f(xu.y)),
                        fast_tanh(s[2] + b2f(xu.z)), fast_tanh(s[3] + b2f(xu.w))));
        }
      }
      wait_vm0();
      if (lane == 0) st_sc1_u32(fg0 + r, (unsigned)t + 1u);
    }
    __syncthreads();

    // ======== L2: n3 = sigm(Ws2 n1 + bs2); n2 = relu(Ws1 n1 + bs1) -> LDS ========
    pollg(fg0, (unsigned)t + 1u);
    {
      s8v bb[8];
      GL8S0(bb, n1L + (size_t)lr * Hdim + wv * 256 + lg * 8);
      f4v a20 = z4, a21 = z4, a10 = z4, a11 = z4;
#pragma unroll
      for (int i = 0; i < 8; ++i) {
        a20 = __builtin_amdgcn_mfma_f32_16x16x32_bf16(w2f[0][i], bb[i], a20, 0, 0, 0);
        a21 = __builtin_amdgcn_mfma_f32_16x16x32_bf16(w2f[1][i], bb[i], a21, 0, 0, 0);
        a10 = __builtin_amdgcn_mfma_f32_16x16x32_bf16(w1f[0][i], bb[i], a10, 0, 0, 0);
        a11 = __builtin_amdgcn_mfma_f32_16x16x32_bf16(w1f[1][i], bb[i], a11, 0, 0, 0);
      }
      if (lc < 8) {
        *(f4v*)&part[0][wv][lc][lg * 4] = a20;
        *(f4v*)&part[0][wv][lc][16 + lg * 4] = a21;
        *(f4v*)&part[1][wv][lc][lg * 4] = a10;
        *(f4v*)&part[1][wv][lc][16 + lg * 4] = a11;
      }
    }
    __syncthreads();
    if (wv == 0) {
      if (lc < 8) {
#pragma unroll
        for (int ct = 0; ct < 2; ++ct) {
          const int cb2 = ct * 16 + lg * 4;
          f4v s = *(f4v*)&part[0][0][lc][cb2] + *(f4v*)&part[0][1][lc][cb2]
                + *(f4v*)&part[0][2][lc][cb2] + *(f4v*)&part[0][3][lc][cb2];
          f4v b = *(const f4v*)(bs + 2 * Hdim + c0w + cb2);
          st_sc0_64(n3L + (size_t)lc * Hdim + c0w + cb2,
                    pk4(fast_sigm(s[0] + b[0]), fast_sigm(s[1] + b[1]),
                        fast_sigm(s[2] + b[2]), fast_sigm(s[3] + b[3])));
        }
      }
      wait_vm0();
      if (lane == 0) st_sc1_u32(fg2 + r, (unsigned)t + 1u);
    } else if (wv == 2) {
      if (lc < 8) {
#pragma unroll
        for (int ct = 0; ct < 2; ++ct) {
          const int cb2 = ct * 16 + lg * 4;
          f4v s = *(f4v*)&part[1][0][lc][cb2] + *(f4v*)&part[1][1][lc][cb2]
                + *(f4v*)&part[1][2][lc][cb2] + *(f4v*)&part[1][3][lc][cb2];
          f4v b = *(const f4v*)(bs + 1 * Hdim + c0w + cb2);
          f4v o; o[0] = fmaxf(s[0] + b[0], 0.f); o[1] = fmaxf(s[1] + b[1], 0.f);
                 o[2] = fmaxf(s[2] + b[2], 0.f); o[3] = fmaxf(s[3] + b[3], 0.f);
          *(f4v*)&n2l[lc][cb2] = o;
        }
      }
    }
    __syncthreads();

    // ======== L3: n5 = relu(Ws4 n3 + bs4); n4 = tanh(Ws3 n3 + bs3) -> LDS ========
    pollg(fg2, (unsigned)t + 1u);
    {
      s8v bb[8];
      GL8S0(bb, n3L + (size_t)lr * Hdim + wv * 256 + lg * 8);
      f4v a40 = z4, a41 = z4, a30 = z4, a31 = z4;
#pragma unroll
      for (int i = 0; i < 8; ++i) {
        a40 = __builtin_amdgcn_mfma_f32_16x16x32_bf16(w4f[0][i], bb[i], a40, 0, 0, 0);
        a41 = __builtin_amdgcn_mfma_f32_16x16x32_bf16(w4f[1][i], bb[i], a41, 0, 0, 0);
        a30 = __builtin_amdgcn_mfma_f32_16x16x32_bf16(w3f[0][i], bb[i], a30, 0, 0, 0);
        a31 = __builtin_amdgcn_mfma_f32_16x16x32_bf16(w3f[1][i], bb[i], a31, 0, 0, 0);
      }
      if (lc < 8) {
        *(f4v*)&part[0][wv][lc][lg * 4] = a40;
        *(f4v*)&part[0][wv][lc][16 + lg * 4] = a41;
        *(f4v*)&part[1][wv][lc][lg * 4] = a30;
        *(f4v*)&part[1][wv][lc][16 + lg * 4] = a31;
      }
    }
    __syncthreads();
    if (wv == 0) {
      if (lc < 8) {
#pragma unroll
        for (int ct = 0; ct < 2; ++ct) {
          const int cb2 = ct * 16 + lg * 4;
          f4v s = *(f4v*)&part[0][0][lc][cb2] + *(f4v*)&part[0][1][lc][cb2]
                + *(f4v*)&part[0][2][lc][cb2] + *(f4v*)&part[0][3][lc][cb2];
          f4v b = *(const f4v*)(bs + 4 * Hdim + c0w + cb2);
          st_sc0_64(n5L + (size_t)lc * Hdim + c0w + cb2,
                    pk4(fmaxf(s[0] + b[0], 0.f), fmaxf(s[1] + b[1], 0.f),
                        fmaxf(s[2] + b[2], 0.f), fmaxf(s[3] + b[3], 0.f)));
        }
      }
      wait_vm0();
      if (lane == 0) st_sc1_u32(fg4 + r, (unsigned)t + 1u);
    } else if (wv == 2) {
      if (lc < 8) {
#pragma unroll
        for (int ct = 0; ct < 2; ++ct) {
          const int cb2 = ct * 16 + lg * 4;
          f4v s = *(f4v*)&part[1][0][lc][cb2] + *(f4v*)&part[1][1][lc][cb2]
                + *(f4v*)&part[1][2][lc][cb2] + *(f4v*)&part[1][3][lc][cb2];
          f4v b = *(const f4v*)(bs + 3 * Hdim + c0w + cb2);
          f4v o; o[0] = fast_tanh(s[0] + b[0]); o[1] = fast_tanh(s[1] + b[1]);
                 o[2] = fast_tanh(s[2] + b[2]); o[3] = fast_tanh(s[3] + b[3]);
          *(f4v*)&n4l[lc][cb2] = o;
        }
      }
    }
    __syncthreads();

    // ======== L4: n6 = tanh(Ws5 n5 + bs5); h' = cw.(n2,n4,n6) ========
    pollg(fg4, (unsigned)t + 1u);
    {
      s8v bb[8];
      GL8S0(bb, n5L + (size_t)lr * Hdim + wv * 256 + lg * 8);
      f4v a0 = z4, a1 = z4;
#pragma unroll
      for (int i = 0; i < 8; ++i) {
        a0 = __builtin_amdgcn_mfma_f32_16x16x32_bf16(w5f[0][i], bb[i], a0, 0, 0, 0);
        a1 = __builtin_amdgcn_mfma_f32_16x16x32_bf16(w5f[1][i], bb[i], a1, 0, 0, 0);
      }
      if (lc < 8) {
        *(f4v*)&part[0][wv][lc][lg * 4] = a0;
        *(f4v*)&part[0][wv][lc][16 + lg * 4] = a1;
      }
    }
    __syncthreads();
    if (wv == 0) {
      if (lc < 8) {
#pragma unroll
        for (int ct = 0; ct < 2; ++ct) {
          const int cb2 = ct * 16 + lg * 4;
          f4v s = *(f4v*)&part[0][0][lc][cb2] + *(f4v*)&part[0][1][lc][cb2]
                + *(f4v*)&part[0][2][lc][cb2] + *(f4v*)&part[0][3][lc][cb2];
          f4v b = *(const f4v*)(bs + 5 * Hdim + c0w + cb2);
          float hv[4];
#pragma unroll
          for (int j = 0; j < 4; ++j) {
            const float n6 = fast_tanh(s[j] + b[j]);
            hv[j] = cw0 * n2l[lc][cb2 + j] + cw1 * n4l[lc][cb2 + j] + cw2 * n6;
          }
          u2v pk = pk4(hv[0], hv[1], hv[2], hv[3]);
          st_sc0_64(hL + (size_t)lc * Hdim + c0w + cb2, pk);
          if (t == TST - 1)
            *(u2v*)(HB + (size_t)(xcd * 8 + lc) * Hdim + c0w + cb2) = pk;
        }
      }
      wait_vm0();
      if (lane == 0) st_sc1_u32(fg5 + r, (unsigned)t + 2u);
    }
    __syncthreads();
  }
}

// ---------------- epilogue: out = h @ W_out^T + b_out ----------------
__global__ __launch_bounds__(256) void k_out(const unsigned short* __restrict__ hb,
                                             const float* __restrict__ wout,
                                             const float* __restrict__ bout,
                                             float* __restrict__ out) {
  const int cb = blockIdx.x * 128;
  const int lane = threadIdx.x & 63, wvv = threadIdx.x >> 6;
  const int lc = lane & 15, lg = lane >> 4;
  const int cw = cb + wvv * 32;
  f4v acc[4][2];
#pragma unroll
  for (int rt = 0; rt < 4; ++rt)
#pragma unroll
    for (int ct = 0; ct < 2; ++ct) acc[rt][ct] = (f4v){0.f, 0.f, 0.f, 0.f};

  for (int ks = 0; ks < 32; ++ks) {
    s8v a[4];
#pragma unroll
    for (int rt = 0; rt < 4; ++rt)
      a[rt] = *(const s8v*)(hb + (rt * 16 + lc) * Hdim + ks * 32 + lg * 8);
#pragma unroll
    for (int ct = 0; ct < 2; ++ct) {
      const int col = cw + ct * 16 + lc;
      const int cs = col < NCLS ? col : NCLS - 1;
      s8v b = pack8(wout + (size_t)cs * Hdim + ks * 32 + lg * 8);
#pragma unroll
      for (int rt = 0; rt < 4; ++rt)
        acc[rt][ct] = __builtin_amdgcn_mfma_f32_16x16x32_bf16(a[rt], b, acc[rt][ct], 0, 0, 0);
    }
  }
#pragma unroll
  for (int ct = 0; ct < 2; ++ct) {
    const int col = cw + ct * 16 + lc;
    if (col < NCLS) {
      const float bias = bout[col];
#pragma unroll
      for (int rt = 0; rt < 4; ++rt)
#pragma unroll
        for (int j = 0; j < 4; ++j)
          out[(size_t)(rt * 16 + lg * 4 + j) * NCLS + col] = acc[rt][ct][j] + bias;
    }
  }
}

extern "C" void kernel_launch(void* const* d_in, const int* in_sizes, int n_in,
                              void* d_out, int out_size, void* d_ws, size_t ws_size,
                              hipStream_t stream) {
  (void)in_sizes; (void)n_in; (void)out_size;
  if (ws_size < WS_NEED) return;

  const float* emb  = (const float*)d_in[0];
  const float* h0   = (const float*)d_in[1];
  const int*   ids  = (const int*)d_in[2];
  const float* W0   = (const float*)d_in[3];
  const float* b0   = (const float*)d_in[4];
  const float* Ws   = (const float*)d_in[5];
  const float* bsp  = (const float*)d_in[6];
  const float* Wout = (const float*)d_in[7];
  const float* bout = (const float*)d_in[8];
  const float* Wsum = (const float*)d_in[9];
  const float* bsum = (const float*)d_in[10];
  const float* actv = (const float*)d_in[11];
  char* ws  = (char*)d_ws;
  float* out = (float*)d_out;

  hipMemsetAsync(ws + OFF_FLG, 0, 8192, stream);                      // flags + ranks
  k_cvt<<<1024, 256, 0, stream>>>(W0, (unsigned short*)(ws + OFF_W0B));
  k_cvt<<<6144, 256, 0, stream>>>(Ws, (unsigned short*)(ws + OFF_WSB));
  k_x0<<<dim3(TST, 4), 256, 0, stream>>>(emb, ids, (const unsigned short*)(ws + OFF_W0B),
                                         b0, bsp, (unsigned short*)(ws + OFF_X0));

  void* args[] = { (void*)&bsp, (void*)&h0, (void*)&Wsum,
                   (void*)&bsum, (void*)&actv, (void*)&ws };
  hipError_t e = hipLaunchCooperativeKernel((void*)k_scan, dim3(256), dim3(256), args, 0, stream);
  if (e != hipSuccess) {
    // fallback: 1 WG/CU is forced by 92 KB LDS, so 256 WGs are co-resident anyway;
    // all polls are guarded -> worst case wrong answer, never a hang.
    k_scan<<<dim3(256), dim3(256), 0, stream>>>(bsp, h0, Wsum, bsum, actv, ws);
  }

  k_out<<<391, 256, 0, stream>>>((const unsigned short*)(ws + OFF_HB), Wout, bout, out);
}

// Round 13
// 1795.034 us; speedup vs baseline: 7.5959x; 1.1045x over previous
//
#include <hip/hip_runtime.h>
#include <hip/hip_bf16.h>

#define Hdim 1024
#define TST  127
#define NCLS 50000
#define POLL_GUARD (1 << 17)

typedef __attribute__((ext_vector_type(8))) short    s8v;   // 8 x bf16
typedef __attribute__((ext_vector_type(4))) float    f4v;   // MFMA acc
typedef __attribute__((ext_vector_type(2))) unsigned u2v;   // packed 4 x bf16

// ---- workspace layout (bytes) ----
#define OFF_X0   0ull
#define SZ_X0    ((unsigned long long)TST * 64 * Hdim * 2ull)   // 16,646,144 bf16 X0
#define OFF_W0B  (OFF_X0 + SZ_X0)                                // 2 MB bf16 embedding W0
#define OFF_WSB  (OFF_W0B + 2097152ull)                          // 12 MB bf16 Ws[6]
#define OFF_ACT  (OFF_WSB + 12582912ull)                         // 8 xcd x 4 bufs x 16 KB
#define OFF_HB   (OFF_ACT + 524288ull)                           // final h [64][1024] bf16
#define OFF_FLG  (OFF_HB + 131072ull)                            // flags[8][6][32] + ranks[8]
#define WS_NEED  (OFF_FLG + 8192ull)

__device__ __forceinline__ unsigned short f2b(float f) {
  union { float f; unsigned u; } v; v.f = f;
  return (unsigned short)((v.u + 0x7FFFu + ((v.u >> 16) & 1u)) >> 16);  // RNE
}
__device__ __forceinline__ float b2f(unsigned short u) {
  union { unsigned u; float f; } v; v.u = ((unsigned)u) << 16;
  return v.f;
}
__device__ __forceinline__ float fast_tanh(float x) { return 1.f - 2.f / (__expf(2.f * x) + 1.f); }
__device__ __forceinline__ float fast_sigm(float x) { return 1.f / (1.f + __expf(-x)); }
__device__ __forceinline__ s8v pack8(const float* __restrict__ p) {
  s8v r;
#pragma unroll
  for (int i = 0; i < 8; ++i) r[i] = (short)f2b(p[i]);
  return r;
}
__device__ __forceinline__ u2v pk4(float a, float b, float c, float d) {
  u2v v;
  v[0] = (unsigned)f2b(a) | ((unsigned)f2b(b) << 16);
  v[1] = (unsigned)f2b(c) | ((unsigned)f2b(d) << 16);
  return v;
}

// ---- access helpers: sc1 = L3 coherence point; sc0 = L1-bypass, own-XCD L2 ----
__device__ __forceinline__ void st_sc1_u32(unsigned* p, unsigned v) {
  asm volatile("global_store_dword %0, %1, off sc0 sc1" :: "v"(p), "v"(v) : "memory");
}
__device__ __forceinline__ void st_sc0_u32(unsigned* p, unsigned v) {
  asm volatile("global_store_dword %0, %1, off sc0" :: "v"(p), "v"(v) : "memory");
}
__device__ __forceinline__ void st_sc0_64(unsigned short* p, u2v v) {
  asm volatile("global_store_dwordx2 %0, %1, off sc0" :: "v"(p), "v"(v) : "memory");
}
__device__ __forceinline__ void wait_vm0() { asm volatile("s_waitcnt vmcnt(0)" ::: "memory"); }

// poll 32 sc1 flags (lane & 31) >= tgt; one load + drain per iter (R3 lesson: one block)
__device__ __forceinline__ void pollg(const unsigned* fb, unsigned tgt) {
  const unsigned* p = fb + (threadIdx.x & 31);
  int gd = 0;
  for (;;) {
    unsigned v;
    asm volatile("global_load_dword %0, %1, off sc0 sc1\n\ts_waitcnt vmcnt(0)"
                 : "=v"(v) : "v"(p) : "memory");
    if (__all((int)(v >= tgt))) break;
    if (++gd >= POLL_GUARD) break;
  }
}

// 8 sc0 dwordx4 act loads + drain in ONE asm block (9 operands, proven scale)
#define GL8S0(B, P) asm volatile(                                       \
  "global_load_dwordx4 %0, %8, off sc0\n\t"                             \
  "global_load_dwordx4 %1, %8, off offset:64 sc0\n\t"                   \
  "global_load_dwordx4 %2, %8, off offset:128 sc0\n\t"                  \
  "global_load_dwordx4 %3, %8, off offset:192 sc0\n\t"                  \
  "global_load_dwordx4 %4, %8, off offset:256 sc0\n\t"                  \
  "global_load_dwordx4 %5, %8, off offset:320 sc0\n\t"                  \
  "global_load_dwordx4 %6, %8, off offset:384 sc0\n\t"                  \
  "global_load_dwordx4 %7, %8, off offset:448 sc0\n\t"                  \
  "s_waitcnt vmcnt(0)"                                                  \
  : "=&v"(B[0]), "=&v"(B[1]), "=&v"(B[2]), "=&v"(B[3]),                 \
    "=&v"(B[4]), "=&v"(B[5]), "=&v"(B[6]), "=&v"(B[7])                  \
  : "v"(P) : "memory")

// ---------------- fp32 -> bf16 bulk convert (W0 and Ws) ----------------
__global__ __launch_bounds__(256) void k_cvt(const float* __restrict__ src,
                                             unsigned short* __restrict__ dst) {
  const int i = (blockIdx.x * 256 + threadIdx.x) * 4;
  float4 v = *(const float4*)(src + i);
  ushort4 o; o.x = f2b(v.x); o.y = f2b(v.y); o.z = f2b(v.z); o.w = f2b(v.w);
  *(ushort4*)(dst + i) = o;
}

// ---------------- X0[t] = emb[idx[:,t+1]] @ W0^T + b0 + bs0, bf16 out ----------------
__global__ __launch_bounds__(256) void k_x0(const float* __restrict__ emb,
                                            const int* __restrict__ ids,
                                            const unsigned short* __restrict__ w0b,
                                            const float* __restrict__ b0,
                                            const float* __restrict__ bs,
                                            unsigned short* __restrict__ x0b) {
  const int t  = blockIdx.x;            // 0..126
  const int cb = blockIdx.y * 256;
  const int lane = threadIdx.x & 63, wvv = threadIdx.x >> 6;
  const int lc = lane & 15, lg = lane >> 4;
  const int cw = cb + wvv * 64;
  const float* erow[4];
#pragma unroll
  for (int rt = 0; rt < 4; ++rt)
    erow[rt] = emb + (size_t)ids[(rt * 16 + lc) * 128 + t + 1] * Hdim + lg * 8;
  f4v acc[4][4];   // [ct][rt]
#pragma unroll
  for (int ct = 0; ct < 4; ++ct)
#pragma unroll
    for (int rt = 0; rt < 4; ++rt) acc[ct][rt] = (f4v){0.f, 0.f, 0.f, 0.f};

  for (int ks = 0; ks < 32; ++ks) {
    s8v bf[4];
#pragma unroll
    for (int rt = 0; rt < 4; ++rt) bf[rt] = pack8(erow[rt] + ks * 32);
#pragma unroll
    for (int ct = 0; ct < 4; ++ct) {
      s8v a = *(const s8v*)(w0b + (size_t)(cw + ct * 16 + lc) * Hdim + ks * 32 + lg * 8);
#pragma unroll
      for (int rt = 0; rt < 4; ++rt)
        acc[ct][rt] = __builtin_amdgcn_mfma_f32_16x16x32_bf16(a, bf[rt], acc[ct][rt], 0, 0, 0);
    }
  }
  unsigned short* xt = x0b + (size_t)t * (64 * Hdim);
#pragma unroll
  for (int ct = 0; ct < 4; ++ct) {
    const int colq = cw + ct * 16 + lg * 4;
    float4 bias = *(const float4*)(b0 + colq);
    float4 bsv  = *(const float4*)(bs + colq);     // bs row 0
#pragma unroll
    for (int rt = 0; rt < 4; ++rt) {
      const int row = rt * 16 + lc;
      ushort4 o;
      o.x = f2b(acc[ct][rt][0] + bias.x + bsv.x);
      o.y = f2b(acc[ct][rt][1] + bias.y + bsv.y);
      o.z = f2b(acc[ct][rt][2] + bias.z + bsv.z);
      o.w = f2b(acc[ct][rt][3] + bias.w + bsv.w);
      *(ushort4*)(xt + (size_t)row * Hdim + colq) = o;
    }
  }
}

// ---------------- persistent scan: 8 independent XCD-local row chains ----------------
__global__ __launch_bounds__(256, 1) void k_scan(const float* __restrict__ bs,
                                                 const float* __restrict__ h_in,
                                                 const float* __restrict__ Wsum,
                                                 const float* __restrict__ bsum,
                                                 const float* __restrict__ act,
                                                 char* __restrict__ ws) {
  __shared__ float part[2][4][8][36];    // padded stride 144B: 2-way (free) reduce reads
  __shared__ float n2l[8][36];
  __shared__ float n4l[8][36];
  __shared__ char  pad_lds[81920];       // forces 1 WG/CU -> exactly 32 WG/XCD
  __shared__ int   s_info[2];

  const int tid = threadIdx.x;
  ((volatile char*)pad_lds)[tid] = (char)tid;              // volatile: not eliminable
  asm volatile("" :: "v"((int)((volatile char*)pad_lds)[tid]));

  const int lane = tid & 63, wv = tid >> 6;
  const int lc = lane & 15, lg = lane >> 4;
  const int lr = lc & 7;                 // act row (rows 8..15 duplicate 0..7)
  const int lcr = lc & 7, ctx = lc >> 3; // reduce remap: all 64 lanes active
  const int cbx = ctx * 16 + lg * 4;     // this lane's 4-col quad in the 32-col slab

  unsigned* flg_all = (unsigned*)(ws + OFF_FLG);
  unsigned* ranks   = flg_all + 1536;

  if (tid == 0) {
    unsigned x;
    asm volatile("s_getreg_b32 %0, hwreg(HW_REG_XCC_ID)" : "=s"(x));
    x &= 7u;
    unsigned rr = __hip_atomic_fetch_add(&ranks[x], 1u, __ATOMIC_RELAXED, __HIP_MEMORY_SCOPE_AGENT);
    s_info[0] = (int)x; s_info[1] = (int)rr;
  }
  __syncthreads();
  const int xcd = s_info[0];
  const int r   = s_info[1];
  if (r >= 32) return;                   // pigeonhole (1 WG/CU) makes this unreachable
  const int c0w = r * 32;

  unsigned short* actX = (unsigned short*)(ws + OFF_ACT) + (size_t)xcd * 32768;
  unsigned short* hL  = actX;            // [8][1024] bf16 per buffer
  unsigned short* n1L = actX + 8192;
  unsigned short* n3L = actX + 16384;
  unsigned short* n5L = actX + 24576;
  unsigned* flgX = flg_all + xcd * 192;  // [6][32]
  unsigned* fg0 = flgX;                  // n1
  unsigned* fg2 = flgX + 64;             // n3
  unsigned* fg4 = flgX + 128;            // n5
  unsigned* fg5 = flgX + 160;            // h
  const unsigned short* wsb = (const unsigned short*)(ws + OFF_WSB);
  const unsigned short* x0b = (const unsigned short*)(ws + OFF_X0);
  unsigned short* HB = (unsigned short*)(ws + OFF_HB);

  // softmax combine weights over leaves {2,4,6} -> Wsum rows {1,3,5}
  float cw0, cw1, cw2;
  {
    float c[3];
#pragma unroll
    for (int j = 0; j < 3; ++j) {
      const int i = 2 * j + 1;
      float s = bsum[i];
      for (int a2 = 0; a2 < 12; ++a2) s += Wsum[i * 12 + a2] * act[a2];
      c[j] = s;
    }
    float m = fmaxf(c[0], fmaxf(c[1], c[2]));
    float e0 = __expf(c[0] - m), e1 = __expf(c[1] - m), e2 = __expf(c[2] - m);
    float inv = 1.f / (e0 + e1 + e2);
    cw0 = e0 * inv; cw1 = e1 * inv; cw2 = e2 * inv;
  }

  // ---- preload resident weights Ws[1..5]: per wave 2 col-tiles x 8 k-chunks each ----
  const size_t wbase = (size_t)(c0w + lc) * Hdim + (size_t)wv * 256 + lg * 8;
  const size_t wct   = (size_t)16 * Hdim;
  s8v w1f[2][8], w2f[2][8], w3f[2][8], w4f[2][8], w5f[2][8];
#pragma unroll
  for (int i = 0; i < 8; ++i) {
    w1f[0][i] = *(const s8v*)(wsb + 1u * 1048576u + wbase + i * 32);
    w1f[1][i] = *(const s8v*)(wsb + 1u * 1048576u + wbase + wct + i * 32);
    w2f[0][i] = *(const s8v*)(wsb + 2u * 1048576u + wbase + i * 32);
    w2f[1][i] = *(const s8v*)(wsb + 2u * 1048576u + wbase + wct + i * 32);
    w3f[0][i] = *(const s8v*)(wsb + 3u * 1048576u + wbase + i * 32);
    w3f[1][i] = *(const s8v*)(wsb + 3u * 1048576u + wbase + wct + i * 32);
    w4f[0][i] = *(const s8v*)(wsb + 4u * 1048576u + wbase + i * 32);
    w4f[1][i] = *(const s8v*)(wsb + 4u * 1048576u + wbase + wct + i * 32);
    w5f[0][i] = *(const s8v*)(wsb + 5u * 1048576u + wbase + i * 32);
    w5f[1][i] = *(const s8v*)(wsb + 5u * 1048576u + wbase + wct + i * 32);
  }

  // ---- init: publish h(0) slice (sc0, own L2), flag g5 = 1 ----
  if (tid < 128) {
    const int row = tid >> 4, cp = (tid & 15) * 2;
    const float* hp = h_in + (size_t)(xcd * 8 + row) * Hdim + c0w + cp;
    unsigned pk = (unsigned)f2b(hp[0]) | ((unsigned)f2b(hp[1]) << 16);
    st_sc0_u32((unsigned*)(hL + (size_t)row * Hdim + c0w + cp), pk);
  }
  wait_vm0();
  __syncthreads();
  if (tid == 0) st_sc1_u32(fg5 + r, 1u);

  const f4v z4 = (f4v){0.f, 0.f, 0.f, 0.f};

  for (int t = 0; t < TST; ++t) {
    // ======== L1: n1 = tanh(Ws0 h + X0[t])  (Ws0 streamed) ========
    pollg(fg5, (unsigned)t + 1u);
    {
      s8v bb[8];
      GL8S0(bb, hL + (size_t)lr * Hdim + wv * 256 + lg * 8);
      unsigned long long w0a = (unsigned long long)wsb;
      asm volatile("" : "+v"(w0a));                  // launder: keep M0 loads in-loop
      const unsigned short* w0p = (const unsigned short*)w0a;
      f4v a0 = z4, a1 = z4;
#pragma unroll
      for (int i = 0; i < 8; ++i) {
        s8v wA = *(const s8v*)(w0p + wbase + i * 32);
        s8v wB = *(const s8v*)(w0p + wbase + wct + i * 32);
        a0 = __builtin_amdgcn_mfma_f32_16x16x32_bf16(wA, bb[i], a0, 0, 0, 0);
        a1 = __builtin_amdgcn_mfma_f32_16x16x32_bf16(wB, bb[i], a1, 0, 0, 0);
      }
      if (lc < 8) {
        *(f4v*)&part[0][wv][lc][lg * 4] = a0;
        *(f4v*)&part[0][wv][lc][16 + lg * 4] = a1;
      }
    }
    __syncthreads();
    if (wv == 0) {
      f4v s = *(f4v*)&part[0][0][lcr][cbx] + *(f4v*)&part[0][1][lcr][cbx]
            + *(f4v*)&part[0][2][lcr][cbx] + *(f4v*)&part[0][3][lcr][cbx];
      ushort4 xu = *(const ushort4*)(x0b + (size_t)t * 65536 +
                                     (size_t)(xcd * 8 + lcr) * Hdim + c0w + cbx);
      st_sc0_64(n1L + (size_t)lcr * Hdim + c0w + cbx,
                pk4(fast_tanh(s[0] + b2f(xu.x)), fast_tanh(s[1] + b2f(xu.y)),
                    fast_tanh(s[2] + b2f(xu.z)), fast_tanh(s[3] + b2f(xu.w))));
      wait_vm0();
      if (lane == 0) st_sc1_u32(fg0 + r, (unsigned)t + 1u);
    }
    __syncthreads();

    // ======== L2: n3 = sigm(Ws2 n1 + bs2); n2 = relu(Ws1 n1 + bs1) -> LDS ========
    pollg(fg0, (unsigned)t + 1u);
    {
      s8v bb[8];
      GL8S0(bb, n1L + (size_t)lr * Hdim + wv * 256 + lg * 8);
      f4v a20 = z4, a21 = z4, a10 = z4, a11 = z4;
#pragma unroll
      for (int i = 0; i < 8; ++i) {
        a20 = __builtin_amdgcn_mfma_f32_16x16x32_bf16(w2f[0][i], bb[i], a20, 0, 0, 0);
        a21 = __builtin_amdgcn_mfma_f32_16x16x32_bf16(w2f[1][i], bb[i], a21, 0, 0, 0);
        a10 = __builtin_amdgcn_mfma_f32_16x16x32_bf16(w1f[0][i], bb[i], a10, 0, 0, 0);
        a11 = __builtin_amdgcn_mfma_f32_16x16x32_bf16(w1f[1][i], bb[i], a11, 0, 0, 0);
      }
      if (lc < 8) {
        *(f4v*)&part[0][wv][lc][lg * 4] = a20;
        *(f4v*)&part[0][wv][lc][16 + lg * 4] = a21;
        *(f4v*)&part[1][wv][lc][lg * 4] = a10;
        *(f4v*)&part[1][wv][lc][16 + lg * 4] = a11;
      }
    }
    __syncthreads();
    if (wv == 0) {
      f4v s = *(f4v*)&part[0][0][lcr][cbx] + *(f4v*)&part[0][1][lcr][cbx]
            + *(f4v*)&part[0][2][lcr][cbx] + *(f4v*)&part[0][3][lcr][cbx];
      f4v b = *(const f4v*)(bs + 2 * Hdim + c0w + cbx);
      st_sc0_64(n3L + (size_t)lcr * Hdim + c0w + cbx,
                pk4(fast_sigm(s[0] + b[0]), fast_sigm(s[1] + b[1]),
                    fast_sigm(s[2] + b[2]), fast_sigm(s[3] + b[3])));
      wait_vm0();
      if (lane == 0) st_sc1_u32(fg2 + r, (unsigned)t + 1u);
    } else if (wv == 2) {
      f4v s = *(f4v*)&part[1][0][lcr][cbx] + *(f4v*)&part[1][1][lcr][cbx]
            + *(f4v*)&part[1][2][lcr][cbx] + *(f4v*)&part[1][3][lcr][cbx];
      f4v b = *(const f4v*)(bs + 1 * Hdim + c0w + cbx);
      f4v o; o[0] = fmaxf(s[0] + b[0], 0.f); o[1] = fmaxf(s[1] + b[1], 0.f);
             o[2] = fmaxf(s[2] + b[2], 0.f); o[3] = fmaxf(s[3] + b[3], 0.f);
      *(f4v*)&n2l[lcr][cbx] = o;
    }
    __syncthreads();

    // ======== L3: n5 = relu(Ws4 n3 + bs4); n4 = tanh(Ws3 n3 + bs3) -> LDS ========
    pollg(fg2, (unsigned)t + 1u);
    {
      s8v bb[8];
      GL8S0(bb, n3L + (size_t)lr * Hdim + wv * 256 + lg * 8);
      f4v a40 = z4, a41 = z4, a30 = z4, a31 = z4;
#pragma unroll
      for (int i = 0; i < 8; ++i) {
        a40 = __builtin_amdgcn_mfma_f32_16x16x32_bf16(w4f[0][i], bb[i], a40, 0, 0, 0);
        a41 = __builtin_amdgcn_mfma_f32_16x16x32_bf16(w4f[1][i], bb[i], a41, 0, 0, 0);
        a30 = __builtin_amdgcn_mfma_f32_16x16x32_bf16(w3f[0][i], bb[i], a30, 0, 0, 0);
        a31 = __builtin_amdgcn_mfma_f32_16x16x32_bf16(w3f[1][i], bb[i], a31, 0, 0, 0);
      }
      if (lc < 8) {
        *(f4v*)&part[0][wv][lc][lg * 4] = a40;
        *(f4v*)&part[0][wv][lc][16 + lg * 4] = a41;
        *(f4v*)&part[1][wv][lc][lg * 4] = a30;
        *(f4v*)&part[1][wv][lc][16 + lg * 4] = a31;
      }
    }
    __syncthreads();
    if (wv == 0) {
      f4v s = *(f4v*)&part[0][0][lcr][cbx] + *(f4v*)&part[0][1][lcr][cbx]
            + *(f4v*)&part[0][2][lcr][cbx] + *(f4v*)&part[0][3][lcr][cbx];
      f4v b = *(const f4v*)(bs + 4 * Hdim + c0w + cbx);
      st_sc0_64(n5L + (size_t)lcr * Hdim + c0w + cbx,
                pk4(fmaxf(s[0] + b[0], 0.f), fmaxf(s[1] + b[1], 0.f),
                    fmaxf(s[2] + b[2], 0.f), fmaxf(s[3] + b[3], 0.f)));
      wait_vm0();
      if (lane == 0) st_sc1_u32(fg4 + r, (unsigned)t + 1u);
    } else if (wv == 2) {
      f4v s = *(f4v*)&part[1][0][lcr][cbx] + *(f4v*)&part[1][1][lcr][cbx]
            + *(f4v*)&part[1][2][lcr][cbx] + *(f4v*)&part[1][3][lcr][cbx];
      f4v b = *(const f4v*)(bs + 3 * Hdim + c0w + cbx);
      f4v o; o[0] = fast_tanh(s[0] + b[0]); o[1] = fast_tanh(s[1] + b[1]);
             o[2] = fast_tanh(s[2] + b[2]); o[3] = fast_tanh(s[3] + b[3]);
      *(f4v*)&n4l[lcr][cbx] = o;
    }
    __syncthreads();

    // ======== L4: n6 = tanh(Ws5 n5 + bs5); h' = cw.(n2,n4,n6) ========
    pollg(fg4, (unsigned)t + 1u);
    {
      s8v bb[8];
      GL8S0(bb, n5L + (size_t)lr * Hdim + wv * 256 + lg * 8);
      f4v a0 = z4, a1 = z4;
#pragma unroll
      for (int i = 0; i < 8; ++i) {
        a0 = __builtin_amdgcn_mfma_f32_16x16x32_bf16(w5f[0][i], bb[i], a0, 0, 0, 0);
        a1 = __builtin_amdgcn_mfma_f32_16x16x32_bf16(w5f[1][i], bb[i], a1, 0, 0, 0);
      }
      if (lc < 8) {
        *(f4v*)&part[0][wv][lc][lg * 4] = a0;
        *(f4v*)&part[0][wv][lc][16 + lg * 4] = a1;
      }
    }
    __syncthreads();
    if (wv == 0) {
      f4v s = *(f4v*)&part[0][0][lcr][cbx] + *(f4v*)&part[0][1][lcr][cbx]
            + *(f4v*)&part[0][2][lcr][cbx] + *(f4v*)&part[0][3][lcr][cbx];
      f4v b = *(const f4v*)(bs + 5 * Hdim + c0w + cbx);
      float hv[4];
#pragma unroll
      for (int j = 0; j < 4; ++j) {
        const float n6 = fast_tanh(s[j] + b[j]);
        hv[j] = cw0 * n2l[lcr][cbx + j] + cw1 * n4l[lcr][cbx + j] + cw2 * n6;
      }
      u2v pk = pk4(hv[0], hv[1], hv[2], hv[3]);
      st_sc0_64(hL + (size_t)lcr * Hdim + c0w + cbx, pk);
      if (t == TST - 1)
        *(u2v*)(HB + (size_t)(xcd * 8 + lcr) * Hdim + c0w + cbx) = pk;
      wait_vm0();
      if (lane == 0) st_sc1_u32(fg5 + r, (unsigned)t + 2u);
    }
    __syncthreads();
  }
}

// ---------------- epilogue: out = h @ W_out^T + b_out ----------------
__global__ __launch_bounds__(256) void k_out(const unsigned short* __restrict__ hb,
                                             const float* __restrict__ wout,
                                             const float* __restrict__ bout,
                                             float* __restrict__ out) {
  const int cb = blockIdx.x * 128;
  const int lane = threadIdx.x & 63, wvv = threadIdx.x >> 6;
  const int lc = lane & 15, lg = lane >> 4;
  const int cw = cb + wvv * 32;
  f4v acc[4][2];
#pragma unroll
  for (int rt = 0; rt < 4; ++rt)
#pragma unroll
    for (int ct = 0; ct < 2; ++ct) acc[rt][ct] = (f4v){0.f, 0.f, 0.f, 0.f};

  for (int ks = 0; ks < 32; ++ks) {
    s8v a[4];
#pragma unroll
    for (int rt = 0; rt < 4; ++rt)
      a[rt] = *(const s8v*)(hb + (rt * 16 + lc) * Hdim + ks * 32 + lg * 8);
#pragma unroll
    for (int ct = 0; ct < 2; ++ct) {
      const int col = cw + ct * 16 + lc;
      const int cs = col < NCLS ? col : NCLS - 1;
      s8v b = pack8(wout + (size_t)cs * Hdim + ks * 32 + lg * 8);
#pragma unroll
      for (int rt = 0; rt < 4; ++rt)
        acc[rt][ct] = __builtin_amdgcn_mfma_f32_16x16x32_bf16(a[rt], b, acc[rt][ct], 0, 0, 0);
    }
  }
#pragma unroll
  for (int ct = 0; ct < 2; ++ct) {
    const int col = cw + ct * 16 + lc;
    if (col < NCLS) {
      const float bias = bout[col];
#pragma unroll
      for (int rt = 0; rt < 4; ++rt)
#pragma unroll
        for (int j = 0; j < 4; ++j)
          out[(size_t)(rt * 16 + lg * 4 + j) * NCLS + col] = acc[rt][ct][j] + bias;
    }
  }
}

extern "C" void kernel_launch(void* const* d_in, const int* in_sizes, int n_in,
                              void* d_out, int out_size, void* d_ws, size_t ws_size,
                              hipStream_t stream) {
  (void)in_sizes; (void)n_in; (void)out_size;
  if (ws_size < WS_NEED) return;

  const float* emb  = (const float*)d_in[0];
  const float* h0   = (const float*)d_in[1];
  const int*   ids  = (const int*)d_in[2];
  const float* W0   = (const float*)d_in[3];
  const float* b0   = (const float*)d_in[4];
  const float* Ws   = (const float*)d_in[5];
  const float* bsp  = (const float*)d_in[6];
  const float* Wout = (const float*)d_in[7];
  const float* bout = (const float*)d_in[8];
  const float* Wsum = (const float*)d_in[9];
  const float* bsum = (const float*)d_in[10];
  const float* actv = (const float*)d_in[11];
  char* ws  = (char*)d_ws;
  float* out = (float*)d_out;

  hipMemsetAsync(ws + OFF_FLG, 0, 8192, stream);                      // flags + ranks
  k_cvt<<<1024, 256, 0, stream>>>(W0, (unsigned short*)(ws + OFF_W0B));
  k_cvt<<<6144, 256, 0, stream>>>(Ws, (unsigned short*)(ws + OFF_WSB));
  k_x0<<<dim3(TST, 4), 256, 0, stream>>>(emb, ids, (const unsigned short*)(ws + OFF_W0B),
                                         b0, bsp, (unsigned short*)(ws + OFF_X0));

  void* args[] = { (void*)&bsp, (void*)&h0, (void*)&Wsum,
                   (void*)&bsum, (void*)&actv, (void*)&ws };
  hipError_t e = hipLaunchCooperativeKernel((void*)k_scan, dim3(256), dim3(256), args, 0, stream);
  if (e != hipSuccess) {
    // fallback: 1 WG/CU forced by ~93 KB LDS -> 256 WGs co-resident anyway;
    // all polls guarded -> worst case wrong answer, never a hang.
    k_scan<<<dim3(256), dim3(256), 0, stream>>>(bsp, h0, Wsum, bsum, actv, ws);
  }

  k_out<<<391, 256, 0, stream>>>((const unsigned short*)(ws + OFF_HB), Wout, bout, out);
}